// Round 6
// baseline (3191.671 us; speedup 1.0000x reference)
//
#include <hip/hip_runtime.h>

#define EPS_LN 1e-5f

constexpr int Dm   = 768;
constexpr int Bb   = 4;
constexpr int Ls   = 1024;
constexpr int Hh   = 12;
constexpr int HD   = 64;
constexpr int ROWS = Bb * Ls;            // 4096
constexpr size_t S = (size_t)ROWS * Dm;  // 3,145,728

// ---- LayerNorm (fp32). LS: additionally divide by lengthscale ----
template<bool LS>
__global__ void __launch_bounds__(256) ln_naive(
    const float* __restrict__ xin,
    const float* __restrict__ scale,
    const float* __restrict__ shift,
    const float* __restrict__ ls,
    float* __restrict__ o)
{
  int row = blockIdx.x;
  int t = threadIdx.x;
  __shared__ float red[256];
  size_t base = (size_t)row * Dm;
  float v0 = xin[base + t];
  float v1 = xin[base + t + 256];
  float v2 = xin[base + t + 512];
  red[t] = v0 + v1 + v2; __syncthreads();
  for (int oo = 128; oo > 0; oo >>= 1) { if (t < oo) red[t] += red[t + oo]; __syncthreads(); }
  float mean = red[0] * (1.0f / Dm);
  __syncthreads();
  float d0 = v0 - mean, d1 = v1 - mean, d2 = v2 - mean;
  red[t] = d0*d0 + d1*d1 + d2*d2; __syncthreads();
  for (int oo = 128; oo > 0; oo >>= 1) { if (t < oo) red[t] += red[t + oo]; __syncthreads(); }
  float rstd = rsqrtf(red[0] * (1.0f / Dm) + EPS_LN);
  float dd[3] = {d0, d1, d2};
  #pragma unroll
  for (int i = 0; i < 3; i++) {
    int c = t + 256 * i;
    float hv = scale[c] * dd[i] * rstd + shift[c];
    if (LS) hv /= ls[c];
    o[base + c] = hv;
  }
}

// ---- naive GEMM: one thread per (row, col). A fp32 [ROWS,Dm]; B fp32 [Dm,Dm].
// MODE 0: outF = acc
// MODE 1: outF = resid + acc + bias           (x1 = x + ctx@Wo + bo)
// MODE 2: outF = resid + acc + bias           (out = x1 + Km@Wf + bf) -> d_out
template<int MODE>
__global__ void __launch_bounds__(256) ngemm(
    const float* __restrict__ A,
    const float* __restrict__ B,
    const float* __restrict__ bias,
    const float* __restrict__ resid,
    float* __restrict__ outF)
{
  int c = blockIdx.x * 256 + threadIdx.x;   // 0..767
  int r = blockIdx.y;                        // 0..4095
  const float* ar = A + (size_t)r * Dm;
  float acc = 0.f;
  #pragma unroll 4
  for (int k = 0; k < Dm; k++)
    acc = fmaf(ar[k], B[(size_t)k * Dm + c], acc);
  size_t idx = (size_t)r * Dm + c;
  if (MODE == 0) outF[idx] = acc;
  else           outF[idx] = resid[idx] + acc + bias[c];
}

// ---- cfT[k*Dm + j] = centers[j,k] / ls[k] ----
__global__ void __launch_bounds__(256) cft_kernel(
    const float* __restrict__ centers,
    const float* __restrict__ ls,
    float* __restrict__ cfT)
{
  int j = blockIdx.x * 256 + threadIdx.x;   // center row -> Km col
  int k = blockIdx.y;                        // dim
  cfT[(size_t)k * Dm + j] = centers[(size_t)j * Dm + k] / ls[k];
}

// ---- Km[r,j] = exp(-0.5 * sum_k (hf[r,k] - cfT[k,j])^2) ----
__global__ void __launch_bounds__(256) rbf_naive(
    const float* __restrict__ hf,
    const float* __restrict__ cfT,
    float* __restrict__ Km)
{
  int j = blockIdx.x * 256 + threadIdx.x;
  int r = blockIdx.y;
  const float* hr = hf + (size_t)r * Dm;
  float acc = 0.f;
  #pragma unroll 4
  for (int k = 0; k < Dm; k++) {
    float d = hr[k] - cfT[(size_t)k * Dm + j];
    acc = fmaf(d, d, acc);
  }
  Km[(size_t)r * Dm + j] = __expf(-0.5f * acc);
}

// ---- causal attention, one block per (b, head, q); fp32 in/out ----
__global__ void __launch_bounds__(256) attn_naive(
    const float* __restrict__ q,
    const float* __restrict__ k,
    const float* __restrict__ v,
    float* __restrict__ ctx)
{
  int qi = blockIdx.x, hy = blockIdx.y, b = blockIdx.z;
  int t = threadIdx.x;
  __shared__ float qs[HD];
  __shared__ float sc[Ls];
  __shared__ float red[256];
  __shared__ float pacc[4][HD];
  int len = qi + 1;
  int hcol = hy * HD;
  size_t rowq = (size_t)(b * Ls + qi) * Dm + hcol;
  if (t < HD) qs[t] = q[rowq + t];
  __syncthreads();

  float lmax = -1e30f;
  for (int kk = t; kk < len; kk += 256) {
    const float* kr = k + (size_t)(b * Ls + kk) * Dm + hcol;
    float s = 0.f;
    #pragma unroll 8
    for (int d = 0; d < HD; d++) s = fmaf(qs[d], kr[d], s);
    s *= 0.125f;                 // 1/sqrt(64)
    sc[kk] = s;
    lmax = fmaxf(lmax, s);
  }
  red[t] = lmax; __syncthreads();
  for (int o = 128; o > 0; o >>= 1) { if (t < o) red[t] = fmaxf(red[t], red[t + o]); __syncthreads(); }
  float gmax = red[0];
  __syncthreads();
  float lsum = 0.f;
  for (int kk = t; kk < len; kk += 256) {
    float e = __expf(sc[kk] - gmax);
    sc[kk] = e;
    lsum += e;
  }
  red[t] = lsum; __syncthreads();
  for (int o = 128; o > 0; o >>= 1) { if (t < o) red[t] += red[t + o]; __syncthreads(); }
  float inv = 1.0f / red[0];
  __syncthreads();

  int d = t & 63, c = t >> 6;
  float a = 0.f;
  for (int kk = c; kk < len; kk += 4)
    a = fmaf(sc[kk], v[(size_t)(b * Ls + kk) * Dm + hcol + d], a);
  pacc[c][d] = a;
  __syncthreads();
  if (c == 0) {
    float r = (pacc[0][d] + pacc[1][d] + pacc[2][d] + pacc[3][d]) * inv;
    ctx[(size_t)(b * Ls + qi) * Dm + hcol + d] = r;
  }
}

extern "C" void kernel_launch(void* const* d_in, const int* in_sizes, int n_in,
                              void* d_out, int out_size, void* d_ws, size_t ws_size,
                              hipStream_t stream)
{
  const float* x      = (const float*)d_in[0];
  const float* Wq     = (const float*)d_in[1];
  const float* Wk     = (const float*)d_in[2];
  const float* Wv     = (const float*)d_in[3];
  const float* Wo     = (const float*)d_in[4];
  const float* bo     = (const float*)d_in[5];
  const float* scale1 = (const float*)d_in[6];
  const float* shift1 = (const float*)d_in[7];
  const float* scale2 = (const float*)d_in[8];
  const float* shift2 = (const float*)d_in[9];
  const float* centers= (const float*)d_in[10];
  const float* lsp    = (const float*)d_in[11];
  const float* Wf     = (const float*)d_in[12];
  const float* bfv    = (const float*)d_in[13];
  float* out = (float*)d_out;

  // ws layout (fp32): [pad 64] h[S] q[S] k[S] v[S] cfT[Dm*Dm]   (~52.6 MB)
  // lifetime overlays: ctx->h, x1->q, hf->k, Km->v (each source dead first)
  float* wsf = (float*)d_ws;
  float* h   = wsf + 64;
  float* qf  = h  + S;
  float* kf  = qf + S;
  float* vf  = kf + S;
  float* cfT = vf + S;
  float* ctx = h;
  float* x1  = qf;
  float* hf  = kf;
  float* Km  = vf;

  dim3 gG(Dm / 256, ROWS);   // (3, 4096)

  // h = LN1(x)
  ln_naive<false><<<ROWS, 256, 0, stream>>>(x, scale1, shift1, nullptr, h);
  // q,k,v = h @ {Wq,Wk,Wv}
  ngemm<0><<<gG, 256, 0, stream>>>(h, Wq, nullptr, nullptr, qf);
  ngemm<0><<<gG, 256, 0, stream>>>(h, Wk, nullptr, nullptr, kf);
  ngemm<0><<<gG, 256, 0, stream>>>(h, Wv, nullptr, nullptr, vf);
  // ctx = causal softmax(q k^T / 8) v    (overwrites h)
  attn_naive<<<dim3(Ls, Hh, Bb), 256, 0, stream>>>(qf, kf, vf, ctx);
  // x1 = x + ctx@Wo + bo                 (overwrites q)
  ngemm<1><<<gG, 256, 0, stream>>>(ctx, Wo, bo, x, x1);
  // hf = LN2(x1)/ls                      (overwrites k)
  ln_naive<true><<<ROWS, 256, 0, stream>>>(x1, scale2, shift2, lsp, hf);
  // cfT = (centers/ls)^T
  cft_kernel<<<dim3(Dm / 256, Dm), 256, 0, stream>>>(centers, lsp, cfT);
  // Km = exp(-0.5 ||hf_r - cf_j||^2)     (overwrites v)
  rbf_naive<<<gG, 256, 0, stream>>>(hf, cfT, Km);
  // out = x1 + Km@Wf + bf  -> d_out (fp32)
  ngemm<2><<<gG, 256, 0, stream>>>(Km, Wf, bfv, x1, out);
}

// Round 7
// 1220.342 us; speedup vs baseline: 2.6154x; 2.6154x over previous
//
#include <hip/hip_runtime.h>

#define EPS_LN 1e-5f

constexpr int Dm   = 768;
constexpr int Bb   = 4;
constexpr int Ls   = 1024;
constexpr int Hh   = 12;
constexpr int HD   = 64;
constexpr int ROWS = Bb * Ls;            // 4096
constexpr size_t S = (size_t)ROWS * Dm;  // 3,145,728
constexpr size_t WSZ = (size_t)Dm * Dm;  // 589,824

typedef __attribute__((ext_vector_type(8))) short bf16x8;
typedef __attribute__((ext_vector_type(4))) float f32x4;

__device__ __forceinline__ float u16tof(unsigned short u) {
  union { unsigned int i; float f; } v; v.i = ((unsigned int)u) << 16; return v.f;
}
__device__ __forceinline__ unsigned short f2bf(float f) {
  unsigned int u = __float_as_uint(f);
  u += 0x7fffu + ((u >> 16) & 1u);   // RNE
  return (unsigned short)(u >> 16);
}

// ---- transpose + cast: WT_bf16[n][k] = bf16(W[k][n]), one weight per blockIdx.z ----
__global__ void __launch_bounds__(256) wt_kernel(
    const float* __restrict__ W0, const float* __restrict__ W1,
    const float* __restrict__ W2, const float* __restrict__ W3,
    const float* __restrict__ W4, unsigned short* __restrict__ outBase)
{
  const float* W = blockIdx.z == 0 ? W0 : blockIdx.z == 1 ? W1 :
                   blockIdx.z == 2 ? W2 : blockIdx.z == 3 ? W3 : W4;
  unsigned short* WT = outBase + (size_t)blockIdx.z * WSZ;
  __shared__ float L[64][65];
  int k0 = blockIdx.y * 64, n0 = blockIdx.x * 64;
  int c = threadIdx.x & 63, r4 = threadIdx.x >> 6;
  #pragma unroll
  for (int p = 0; p < 16; p++) {
    int r = p * 4 + r4;
    L[r][c] = W[(size_t)(k0 + r) * Dm + n0 + c];
  }
  __syncthreads();
  #pragma unroll
  for (int p = 0; p < 16; p++) {
    int r = p * 4 + r4;
    WT[(size_t)(n0 + r) * Dm + k0 + c] = f2bf(L[c][r]);
  }
}

// ---- cb[j][k] = bf16(centers[j][k] / ls[k])  (already B^T layout for the cross GEMM) ----
__global__ void __launch_bounds__(256) cscale_kernel(
    const float* __restrict__ centers, const float* __restrict__ ls,
    unsigned short* __restrict__ cb)
{
  int k = blockIdx.x * 256 + threadIdx.x;   // 0..767
  int j = blockIdx.y;
  size_t i = (size_t)j * Dm + k;
  cb[i] = f2bf(centers[i] / ls[k]);
}

// ---- cn[j] = sum_k (centers[j][k]/ls[k])^2  (fp32 exact) ----
__global__ void __launch_bounds__(256) cnorm_kernel(
    const float* __restrict__ centers, const float* __restrict__ ls,
    float* __restrict__ cn)
{
  int j = blockIdx.x, t = threadIdx.x;
  __shared__ float red[256];
  float s = 0.f;
  #pragma unroll
  for (int i = 0; i < 3; i++) {
    int k = t + 256 * i;
    float d = centers[(size_t)j * Dm + k] / ls[k];
    s += d * d;
  }
  red[t] = s; __syncthreads();
  for (int o = 128; o > 0; o >>= 1) { if (t < o) red[t] += red[t + o]; __syncthreads(); }
  if (t == 0) cn[j] = red[0];
}

// ---- LN1: fp32 x -> bf16 h ----
__global__ void __launch_bounds__(256) ln1_kernel(
    const float* __restrict__ xin, const float* __restrict__ scale,
    const float* __restrict__ shift, unsigned short* __restrict__ o)
{
  int row = blockIdx.x, t = threadIdx.x;
  __shared__ float red[256];
  size_t base = (size_t)row * Dm;
  float v0 = xin[base + t], v1 = xin[base + t + 256], v2 = xin[base + t + 512];
  red[t] = v0 + v1 + v2; __syncthreads();
  for (int oo = 128; oo > 0; oo >>= 1) { if (t < oo) red[t] += red[t + oo]; __syncthreads(); }
  float mean = red[0] * (1.0f / Dm);
  __syncthreads();
  float d0 = v0 - mean, d1 = v1 - mean, d2 = v2 - mean;
  red[t] = d0*d0 + d1*d1 + d2*d2; __syncthreads();
  for (int oo = 128; oo > 0; oo >>= 1) { if (t < oo) red[t] += red[t + oo]; __syncthreads(); }
  float rstd = rsqrtf(red[0] * (1.0f / Dm) + EPS_LN);
  float dd[3] = {d0, d1, d2};
  #pragma unroll
  for (int i = 0; i < 3; i++) {
    int c = t + 256 * i;
    o[base + c] = f2bf(scale[c] * dd[i] * rstd + shift[c]);
  }
}

// ---- LN2 + /ls: fp32 x1 -> bf16 hf + fp32 hnorm[row] = ||hf||^2 ----
__global__ void __launch_bounds__(256) ln2_kernel(
    const float* __restrict__ xin, const float* __restrict__ scale,
    const float* __restrict__ shift, const float* __restrict__ ls,
    unsigned short* __restrict__ o, float* __restrict__ hn)
{
  int row = blockIdx.x, t = threadIdx.x;
  __shared__ float red[256];
  size_t base = (size_t)row * Dm;
  float v0 = xin[base + t], v1 = xin[base + t + 256], v2 = xin[base + t + 512];
  red[t] = v0 + v1 + v2; __syncthreads();
  for (int oo = 128; oo > 0; oo >>= 1) { if (t < oo) red[t] += red[t + oo]; __syncthreads(); }
  float mean = red[0] * (1.0f / Dm);
  __syncthreads();
  float d0 = v0 - mean, d1 = v1 - mean, d2 = v2 - mean;
  red[t] = d0*d0 + d1*d1 + d2*d2; __syncthreads();
  for (int oo = 128; oo > 0; oo >>= 1) { if (t < oo) red[t] += red[t + oo]; __syncthreads(); }
  float rstd = rsqrtf(red[0] * (1.0f / Dm) + EPS_LN);
  float dd[3] = {d0, d1, d2};
  float hsum = 0.f;
  #pragma unroll
  for (int i = 0; i < 3; i++) {
    int c = t + 256 * i;
    float hv = (scale[c] * dd[i] * rstd + shift[c]) / ls[c];
    o[base + c] = f2bf(hv);
    hsum += hv * hv;
  }
  __syncthreads();
  red[t] = hsum; __syncthreads();
  for (int o2 = 128; o2 > 0; o2 >>= 1) { if (t < o2) red[t] += red[t + o2]; __syncthreads(); }
  if (t == 0) hn[row] = red[0];
}

// =============== MFMA bf16 GEMM, 64x64 tile, fp32 accumulate ===============
// A: bf16 [4096][768] row-major. BT: bf16 [N=768][K=768] row-major (B^T).
// MODE 0: z selects (BT0..2, o0..2); out bf16 = acc          (QKV)
// MODE 1: outF = residF + acc + biasF                        (x1 = x + ctx@Wo + bo)
// MODE 2: o0 bf16 = exp(-0.5*max(hn[r]+cn[c]-2acc, 0))       (RBF kernel matrix)
// MODE 3: outF = residF + acc + biasF                        (d_out = x1 + Km@Wf + bf)
template<int MODE>
__global__ void __launch_bounds__(256) gemm_mfma(
    const unsigned short* __restrict__ Abf,
    const unsigned short* __restrict__ BT0,
    const unsigned short* __restrict__ BT1,
    const unsigned short* __restrict__ BT2,
    unsigned short* __restrict__ o0,
    unsigned short* __restrict__ o1,
    unsigned short* __restrict__ o2,
    float* __restrict__ outF,
    const float* __restrict__ residF,
    const float* __restrict__ biasF,
    const float* __restrict__ hn,
    const float* __restrict__ cn)
{
  const unsigned short* BT = BT0;
  unsigned short* ob = o0;
  if (MODE == 0) {
    if (blockIdx.z == 1) { BT = BT1; ob = o1; }
    else if (blockIdx.z == 2) { BT = BT2; ob = o2; }
  }
  int m0 = blockIdx.y * 64, n0 = blockIdx.x * 64;
  __shared__ unsigned short Asm[64][40];   // 32 k + pad8 (80B stride, 8B aligned)
  __shared__ unsigned short Bsm[64][40];
  int tid = threadIdx.x;
  int lane = tid & 63, wave = tid >> 6;
  int quad = lane >> 4, l15 = lane & 15;
  int wr = (wave >> 1) << 5, wc = (wave & 1) << 5;
  int srow = tid >> 2, skq = (tid & 3) << 3;

  f32x4 acc[2][2];
  #pragma unroll
  for (int i = 0; i < 2; i++)
    #pragma unroll
    for (int j = 0; j < 2; j++) acc[i][j] = (f32x4){0.f, 0.f, 0.f, 0.f};

  const unsigned short* Ag = Abf + (size_t)(m0 + srow) * Dm + skq;
  const unsigned short* Bg = BT  + (size_t)(n0 + srow) * Dm + skq;

  for (int k0 = 0; k0 < Dm; k0 += 32) {
    ushort4 a0 = *(const ushort4*)(Ag + k0);
    ushort4 a1 = *(const ushort4*)(Ag + k0 + 4);
    ushort4 b0 = *(const ushort4*)(Bg + k0);
    ushort4 b1 = *(const ushort4*)(Bg + k0 + 4);
    *(ushort4*)&Asm[srow][skq]     = a0;
    *(ushort4*)&Asm[srow][skq + 4] = a1;
    *(ushort4*)&Bsm[srow][skq]     = b0;
    *(ushort4*)&Bsm[srow][skq + 4] = b1;
    __syncthreads();
    union { bf16x8 v; ushort4 h[2]; } af[2], bfr[2];
    #pragma unroll
    for (int i = 0; i < 2; i++) {
      af[i].h[0]  = *(const ushort4*)&Asm[wr + i * 16 + l15][quad * 8];
      af[i].h[1]  = *(const ushort4*)&Asm[wr + i * 16 + l15][quad * 8 + 4];
      bfr[i].h[0] = *(const ushort4*)&Bsm[wc + i * 16 + l15][quad * 8];
      bfr[i].h[1] = *(const ushort4*)&Bsm[wc + i * 16 + l15][quad * 8 + 4];
    }
    #pragma unroll
    for (int mi = 0; mi < 2; mi++)
      #pragma unroll
      for (int ni = 0; ni < 2; ni++)
        acc[mi][ni] = __builtin_amdgcn_mfma_f32_16x16x32_bf16(
            af[mi].v, bfr[ni].v, acc[mi][ni], 0, 0, 0);
    __syncthreads();
  }

  // C/D layout (verified): col = lane&15, row = quad*4 + reg
  #pragma unroll
  for (int mi = 0; mi < 2; mi++)
    #pragma unroll
    for (int ni = 0; ni < 2; ni++) {
      #pragma unroll
      for (int rg = 0; rg < 4; rg++) {
        int gr = m0 + wr + mi * 16 + quad * 4 + rg;
        int gc = n0 + wc + ni * 16 + l15;
        size_t idx = (size_t)gr * Dm + gc;
        float v = acc[mi][ni][rg];
        if (MODE == 0) {
          ob[idx] = f2bf(v);
        } else if (MODE == 1) {
          outF[idx] = residF[idx] + v + biasF[gc];
        } else if (MODE == 2) {
          float sq = fmaxf(hn[gr] + cn[gc] - 2.0f * v, 0.f);
          o0[idx] = f2bf(__expf(-0.5f * sq));
        } else {
          outF[idx] = residF[idx] + v + biasF[gc];
        }
      }
    }
}

// ---- causal attention, one block per (b, head, q); bf16 in/out ----
__global__ void __launch_bounds__(256) attn_naive(
    const unsigned short* __restrict__ q,
    const unsigned short* __restrict__ k,
    const unsigned short* __restrict__ v,
    unsigned short* __restrict__ ctx)
{
  int qi = blockIdx.x, hy = blockIdx.y, b = blockIdx.z;
  int t = threadIdx.x;
  __shared__ float qs[HD];
  __shared__ float sc[Ls];
  __shared__ float red[256];
  __shared__ float pacc[4][HD];
  int len = qi + 1;
  int hcol = hy * HD;
  size_t rowq = (size_t)(b * Ls + qi) * Dm + hcol;
  if (t < HD) qs[t] = u16tof(q[rowq + t]);
  __syncthreads();

  float lmax = -1e30f;
  for (int kk = t; kk < len; kk += 256) {
    const unsigned short* kr = k + (size_t)(b * Ls + kk) * Dm + hcol;
    float s = 0.f;
    #pragma unroll
    for (int d = 0; d < HD; d += 4) {
      ushort4 kv = *(const ushort4*)(kr + d);
      s += qs[d]     * u16tof(kv.x) + qs[d + 1] * u16tof(kv.y)
         + qs[d + 2] * u16tof(kv.z) + qs[d + 3] * u16tof(kv.w);
    }
    s *= 0.125f;
    sc[kk] = s;
    lmax = fmaxf(lmax, s);
  }
  red[t] = lmax; __syncthreads();
  for (int o = 128; o > 0; o >>= 1) { if (t < o) red[t] = fmaxf(red[t], red[t + o]); __syncthreads(); }
  float gmax = red[0];
  __syncthreads();
  float lsum = 0.f;
  for (int kk = t; kk < len; kk += 256) {
    float e = __expf(sc[kk] - gmax);
    sc[kk] = e;
    lsum += e;
  }
  red[t] = lsum; __syncthreads();
  for (int o = 128; o > 0; o >>= 1) { if (t < o) red[t] += red[t + o]; __syncthreads(); }
  float inv = 1.0f / red[0];
  __syncthreads();

  int d = t & 63, c = t >> 6;
  float a = 0.f;
  for (int kk = c; kk < len; kk += 4)
    a = fmaf(sc[kk], u16tof(v[(size_t)(b * Ls + kk) * Dm + hcol + d]), a);
  pacc[c][d] = a;
  __syncthreads();
  if (c == 0) {
    float r = (pacc[0][d] + pacc[1][d] + pacc[2][d] + pacc[3][d]) * inv;
    ctx[(size_t)(b * Ls + qi) * Dm + hcol + d] = f2bf(r);
  }
}

extern "C" void kernel_launch(void* const* d_in, const int* in_sizes, int n_in,
                              void* d_out, int out_size, void* d_ws, size_t ws_size,
                              hipStream_t stream)
{
  const float* x      = (const float*)d_in[0];
  const float* Wq     = (const float*)d_in[1];
  const float* Wk     = (const float*)d_in[2];
  const float* Wv     = (const float*)d_in[3];
  const float* Wo     = (const float*)d_in[4];
  const float* bo     = (const float*)d_in[5];
  const float* scale1 = (const float*)d_in[6];
  const float* shift1 = (const float*)d_in[7];
  const float* scale2 = (const float*)d_in[8];
  const float* shift2 = (const float*)d_in[9];
  const float* centers= (const float*)d_in[10];
  const float* lsp    = (const float*)d_in[11];
  const float* Wf     = (const float*)d_in[12];
  const float* bfv    = (const float*)d_in[13];
  float* out = (float*)d_out;

  // ws (u16 units): [wt: 6*WSZ] [bufA: S] [bufB: 3S] [hn: ROWS f32] [cn: Dm f32]
  // wt = WqT,WkT,WvT,WoT,WfT,cb. bufA: h -> ctx -> Km. bufB: q,k,v -> x1(f32, 2S u16) + hf(last S).
  unsigned short* wsu = (unsigned short*)d_ws;
  unsigned short* wqT = wsu;
  unsigned short* wkT = wsu + WSZ;
  unsigned short* wvT = wsu + 2 * WSZ;
  unsigned short* woT = wsu + 3 * WSZ;
  unsigned short* wfT = wsu + 4 * WSZ;
  unsigned short* cb  = wsu + 5 * WSZ;
  unsigned short* bufA = wsu + 6 * WSZ;
  unsigned short* bufB = bufA + S;
  unsigned short* hb  = bufA;          // LN1 out
  unsigned short* qb  = bufB;
  unsigned short* kb  = bufB + S;
  unsigned short* vb  = bufB + 2 * S;
  unsigned short* ctx = bufA;          // h dead after QKV
  float* x1f          = (float*)bufB;  // q,k dead after attn (S floats = 2S u16)
  unsigned short* hf  = bufB + 2 * S;  // v dead after attn
  unsigned short* Km  = bufA;          // ctx dead after Wo GEMM
  float* hn = (float*)(bufB + 3 * S);
  float* cn = hn + ROWS;

  dim3 gg(Dm / 64, ROWS / 64);         // (12, 64)

  // one-time weight prep
  wt_kernel<<<dim3(12, 12, 5), 256, 0, stream>>>(Wq, Wk, Wv, Wo, Wf, wsu);
  cscale_kernel<<<dim3(3, Dm), 256, 0, stream>>>(centers, lsp, cb);
  cnorm_kernel<<<Dm, 256, 0, stream>>>(centers, lsp, cn);

  // h = bf16(LN1(x))
  ln1_kernel<<<ROWS, 256, 0, stream>>>(x, scale1, shift1, hb);
  // q,k,v = h @ {Wq,Wk,Wv}
  gemm_mfma<0><<<dim3(12, 64, 3), 256, 0, stream>>>(hb, wqT, wkT, wvT, qb, kb, vb,
                                                    nullptr, nullptr, nullptr, nullptr, nullptr);
  // ctx = causal softmax(q k^T / 8) v
  attn_naive<<<dim3(Ls, Hh, Bb), 256, 0, stream>>>(qb, kb, vb, ctx);
  // x1 = x + ctx@Wo + bo   (fp32)
  gemm_mfma<1><<<gg, 256, 0, stream>>>(ctx, woT, nullptr, nullptr, nullptr, nullptr, nullptr,
                                       x1f, x, bo, nullptr, nullptr);
  // hf = bf16(LN2(x1)/ls), hn = ||hf||^2
  ln2_kernel<<<ROWS, 256, 0, stream>>>(x1f, scale2, shift2, lsp, hf, hn);
  // Km = exp(-0.5*max(hn + cn - 2*hf@cb^T, 0))
  gemm_mfma<2><<<gg, 256, 0, stream>>>(hf, cb, nullptr, nullptr, Km, nullptr, nullptr,
                                       nullptr, nullptr, nullptr, hn, cn);
  // out = x1 + Km@Wf + bf  (fp32 -> d_out)
  gemm_mfma<3><<<gg, 256, 0, stream>>>(Km, wfT, nullptr, nullptr, nullptr, nullptr, nullptr,
                                       out, x1f, bfv, nullptr, nullptr);
}

// Round 8
// 270.670 us; speedup vs baseline: 11.7918x; 4.5086x over previous
//
#include <hip/hip_runtime.h>

#define EPS_LN 1e-5f

constexpr int Dm   = 768;
constexpr int Bb   = 4;
constexpr int Ls   = 1024;
constexpr int Hh   = 12;
constexpr int HD   = 64;
constexpr int ROWS = Bb * Ls;            // 4096
constexpr size_t S = (size_t)ROWS * Dm;  // 3,145,728
constexpr size_t WSZ = (size_t)Dm * Dm;  // 589,824

typedef __attribute__((ext_vector_type(8))) short bf16x8;
typedef __attribute__((ext_vector_type(4))) float f32x4;

__device__ __forceinline__ unsigned short f2bf(float f) {
  unsigned int u = __float_as_uint(f);
  u += 0x7fffu + ((u >> 16) & 1u);   // RNE
  return (unsigned short)(u >> 16);
}

// ---- transpose + cast: WT_bf16[n][k] = bf16(W[k][n]), one weight per blockIdx.z ----
__global__ void __launch_bounds__(256) wt_kernel(
    const float* __restrict__ W0, const float* __restrict__ W1,
    const float* __restrict__ W2, const float* __restrict__ W3,
    const float* __restrict__ W4, unsigned short* __restrict__ outBase)
{
  const float* W = blockIdx.z == 0 ? W0 : blockIdx.z == 1 ? W1 :
                   blockIdx.z == 2 ? W2 : blockIdx.z == 3 ? W3 : W4;
  unsigned short* WT = outBase + (size_t)blockIdx.z * WSZ;
  __shared__ float L[64][65];
  int k0 = blockIdx.y * 64, n0 = blockIdx.x * 64;
  int c = threadIdx.x & 63, r4 = threadIdx.x >> 6;
  #pragma unroll
  for (int p = 0; p < 16; p++) {
    int r = p * 4 + r4;
    L[r][c] = W[(size_t)(k0 + r) * Dm + n0 + c];
  }
  __syncthreads();
  #pragma unroll
  for (int p = 0; p < 16; p++) {
    int r = p * 4 + r4;
    WT[(size_t)(n0 + r) * Dm + k0 + c] = f2bf(L[c][r]);
  }
}

// ---- cb[j][k] = bf16(centers[j][k] / ls[k]) ----
__global__ void __launch_bounds__(256) cscale_kernel(
    const float* __restrict__ centers, const float* __restrict__ ls,
    unsigned short* __restrict__ cb)
{
  int k = blockIdx.x * 256 + threadIdx.x;
  int j = blockIdx.y;
  size_t i = (size_t)j * Dm + k;
  cb[i] = f2bf(centers[i] / ls[k]);
}

// ---- cn[j] = sum_k (centers[j][k]/ls[k])^2 ----
__global__ void __launch_bounds__(256) cnorm_kernel(
    const float* __restrict__ centers, const float* __restrict__ ls,
    float* __restrict__ cn)
{
  int j = blockIdx.x, t = threadIdx.x;
  __shared__ float red[256];
  float s = 0.f;
  #pragma unroll
  for (int i = 0; i < 3; i++) {
    int k = t + 256 * i;
    float d = centers[(size_t)j * Dm + k] / ls[k];
    s += d * d;
  }
  red[t] = s; __syncthreads();
  for (int o = 128; o > 0; o >>= 1) { if (t < o) red[t] += red[t + o]; __syncthreads(); }
  if (t == 0) cn[j] = red[0];
}

// ---- LN1: fp32 x -> bf16 h ----
__global__ void __launch_bounds__(256) ln1_kernel(
    const float* __restrict__ xin, const float* __restrict__ scale,
    const float* __restrict__ shift, unsigned short* __restrict__ o)
{
  int row = blockIdx.x, t = threadIdx.x;
  __shared__ float red[256];
  size_t base = (size_t)row * Dm;
  float v0 = xin[base + t], v1 = xin[base + t + 256], v2 = xin[base + t + 512];
  red[t] = v0 + v1 + v2; __syncthreads();
  for (int oo = 128; oo > 0; oo >>= 1) { if (t < oo) red[t] += red[t + oo]; __syncthreads(); }
  float mean = red[0] * (1.0f / Dm);
  __syncthreads();
  float d0 = v0 - mean, d1 = v1 - mean, d2 = v2 - mean;
  red[t] = d0*d0 + d1*d1 + d2*d2; __syncthreads();
  for (int oo = 128; oo > 0; oo >>= 1) { if (t < oo) red[t] += red[t + oo]; __syncthreads(); }
  float rstd = rsqrtf(red[0] * (1.0f / Dm) + EPS_LN);
  float dd[3] = {d0, d1, d2};
  #pragma unroll
  for (int i = 0; i < 3; i++) {
    int c = t + 256 * i;
    o[base + c] = f2bf(scale[c] * dd[i] * rstd + shift[c]);
  }
}

// ---- LN2 + /ls: fp32 x1 -> bf16 hf + fp32 hnorm[row] ----
__global__ void __launch_bounds__(256) ln2_kernel(
    const float* __restrict__ xin, const float* __restrict__ scale,
    const float* __restrict__ shift, const float* __restrict__ ls,
    unsigned short* __restrict__ o, float* __restrict__ hn)
{
  int row = blockIdx.x, t = threadIdx.x;
  __shared__ float red[256];
  size_t base = (size_t)row * Dm;
  float v0 = xin[base + t], v1 = xin[base + t + 256], v2 = xin[base + t + 512];
  red[t] = v0 + v1 + v2; __syncthreads();
  for (int oo = 128; oo > 0; oo >>= 1) { if (t < oo) red[t] += red[t + oo]; __syncthreads(); }
  float mean = red[0] * (1.0f / Dm);
  __syncthreads();
  float d0 = v0 - mean, d1 = v1 - mean, d2 = v2 - mean;
  red[t] = d0*d0 + d1*d1 + d2*d2; __syncthreads();
  for (int oo = 128; oo > 0; oo >>= 1) { if (t < oo) red[t] += red[t + oo]; __syncthreads(); }
  float rstd = rsqrtf(red[0] * (1.0f / Dm) + EPS_LN);
  float dd[3] = {d0, d1, d2};
  float hsum = 0.f;
  #pragma unroll
  for (int i = 0; i < 3; i++) {
    int c = t + 256 * i;
    float hv = (scale[c] * dd[i] * rstd + shift[c]) / ls[c];
    o[base + c] = f2bf(hv);
    hsum += hv * hv;
  }
  __syncthreads();
  red[t] = hsum; __syncthreads();
  for (int o2 = 128; o2 > 0; o2 >>= 1) { if (t < o2) red[t] += red[t + o2]; __syncthreads(); }
  if (t == 0) hn[row] = red[0];
}

// =============== MFMA bf16 GEMM, 64x64 tile, fp32 accumulate ===============
template<int MODE>
__global__ void __launch_bounds__(256) gemm_mfma(
    const unsigned short* __restrict__ Abf,
    const unsigned short* __restrict__ BT0,
    const unsigned short* __restrict__ BT1,
    const unsigned short* __restrict__ BT2,
    unsigned short* __restrict__ o0,
    unsigned short* __restrict__ o1,
    unsigned short* __restrict__ o2,
    float* __restrict__ outF,
    const float* __restrict__ residF,
    const float* __restrict__ biasF,
    const float* __restrict__ hn,
    const float* __restrict__ cn)
{
  const unsigned short* BT = BT0;
  unsigned short* ob = o0;
  if (MODE == 0) {
    if (blockIdx.z == 1) { BT = BT1; ob = o1; }
    else if (blockIdx.z == 2) { BT = BT2; ob = o2; }
  }
  int m0 = blockIdx.y * 64, n0 = blockIdx.x * 64;
  __shared__ unsigned short Asm[64][40];
  __shared__ unsigned short Bsm[64][40];
  int tid = threadIdx.x;
  int lane = tid & 63, wave = tid >> 6;
  int quad = lane >> 4, l15 = lane & 15;
  int wr = (wave >> 1) << 5, wc = (wave & 1) << 5;
  int srow = tid >> 2, skq = (tid & 3) << 3;

  f32x4 acc[2][2];
  #pragma unroll
  for (int i = 0; i < 2; i++)
    #pragma unroll
    for (int j = 0; j < 2; j++) acc[i][j] = (f32x4){0.f, 0.f, 0.f, 0.f};

  const unsigned short* Ag = Abf + (size_t)(m0 + srow) * Dm + skq;
  const unsigned short* Bg = BT  + (size_t)(n0 + srow) * Dm + skq;

  for (int k0 = 0; k0 < Dm; k0 += 32) {
    ushort4 a0 = *(const ushort4*)(Ag + k0);
    ushort4 a1 = *(const ushort4*)(Ag + k0 + 4);
    ushort4 b0 = *(const ushort4*)(Bg + k0);
    ushort4 b1 = *(const ushort4*)(Bg + k0 + 4);
    *(ushort4*)&Asm[srow][skq]     = a0;
    *(ushort4*)&Asm[srow][skq + 4] = a1;
    *(ushort4*)&Bsm[srow][skq]     = b0;
    *(ushort4*)&Bsm[srow][skq + 4] = b1;
    __syncthreads();
    union { bf16x8 v; ushort4 h[2]; } af[2], bfr[2];
    #pragma unroll
    for (int i = 0; i < 2; i++) {
      af[i].h[0]  = *(const ushort4*)&Asm[wr + i * 16 + l15][quad * 8];
      af[i].h[1]  = *(const ushort4*)&Asm[wr + i * 16 + l15][quad * 8 + 4];
      bfr[i].h[0] = *(const ushort4*)&Bsm[wc + i * 16 + l15][quad * 8];
      bfr[i].h[1] = *(const ushort4*)&Bsm[wc + i * 16 + l15][quad * 8 + 4];
    }
    #pragma unroll
    for (int mi = 0; mi < 2; mi++)
      #pragma unroll
      for (int ni = 0; ni < 2; ni++)
        acc[mi][ni] = __builtin_amdgcn_mfma_f32_16x16x32_bf16(
            af[mi].v, bfr[ni].v, acc[mi][ni], 0, 0, 0);
    __syncthreads();
  }

  #pragma unroll
  for (int mi = 0; mi < 2; mi++)
    #pragma unroll
    for (int ni = 0; ni < 2; ni++) {
      #pragma unroll
      for (int rg = 0; rg < 4; rg++) {
        int gr = m0 + wr + mi * 16 + quad * 4 + rg;
        int gc = n0 + wc + ni * 16 + l15;
        size_t idx = (size_t)gr * Dm + gc;
        float v = acc[mi][ni][rg];
        if (MODE == 0) {
          ob[idx] = f2bf(v);
        } else if (MODE == 1) {
          outF[idx] = residF[idx] + v + biasF[gc];
        } else if (MODE == 2) {
          float sq = fmaxf(hn[gr] + cn[gc] - 2.0f * v, 0.f);
          o0[idx] = f2bf(__expf(-0.5f * sq));
        } else {
          outF[idx] = residF[idx] + v + biasF[gc];
        }
      }
    }
}

// =============== flash attention: one block per (b, h, 64-row Q tile) ===============
// q/k/v/ctx: bf16 [ROWS][768], head h at cols h*64..h*64+63. Causal.
__global__ void __launch_bounds__(256) attn_flash(
    const unsigned short* __restrict__ q,
    const unsigned short* __restrict__ k,
    const unsigned short* __restrict__ v,
    unsigned short* __restrict__ ctx)
{
  int qt = blockIdx.x;     // 0..15
  int h  = blockIdx.y;     // 0..11
  int b  = blockIdx.z;     // 0..3
  int tid = threadIdx.x;
  int lane = tid & 63, wave = tid >> 6;
  int quad = lane >> 4, l15 = lane & 15;

  __shared__ unsigned short Qs[64][72];
  __shared__ unsigned short Ks[64][72];
  __shared__ unsigned short Vt[64][72];   // transposed: Vt[hd][key]
  __shared__ unsigned short Ps[64][72];

  size_t base = (size_t)b * Ls * Dm + h * HD;

  // stage Q tile (64x64): thread t -> row t>>2, cols (t&3)*16..+15
  {
    int r = tid >> 2, c0 = (tid & 3) * 16;
    const unsigned short* src = q + base + (size_t)(qt * 64 + r) * Dm + c0;
    #pragma unroll
    for (int i = 0; i < 16; i += 4)
      *(ushort4*)&Qs[r][c0 + i] = *(const ushort4*)(src + i);
  }

  f32x4 O[4];
  #pragma unroll
  for (int nj = 0; nj < 4; nj++) O[nj] = (f32x4){0.f, 0.f, 0.f, 0.f};
  float mrow[4], lrow[4];
  #pragma unroll
  for (int rg = 0; rg < 4; rg++) { mrow[rg] = -1e30f; lrow[rg] = 0.f; }

  __syncthreads();

  // Q A-frags are loop-invariant: A[m=l15][k=kc*32+quad*8+j]
  union Frag { bf16x8 v; ushort4 h[2]; };
  Frag afq[2];
  afq[0].h[0] = *(const ushort4*)&Qs[wave * 16 + l15][quad * 8];
  afq[0].h[1] = *(const ushort4*)&Qs[wave * 16 + l15][quad * 8 + 4];
  afq[1].h[0] = *(const ushort4*)&Qs[wave * 16 + l15][32 + quad * 8];
  afq[1].h[1] = *(const ushort4*)&Qs[wave * 16 + l15][32 + quad * 8 + 4];

  for (int kt = 0; kt <= qt; kt++) {
    // stage K (row-major) and V (transposed)
    {
      int r = tid >> 2, c0 = (tid & 3) * 16;
      const unsigned short* ks = k + base + (size_t)(kt * 64 + r) * Dm + c0;
      const unsigned short* vs = v + base + (size_t)(kt * 64 + r) * Dm + c0;
      #pragma unroll
      for (int i = 0; i < 16; i += 4)
        *(ushort4*)&Ks[r][c0 + i] = *(const ushort4*)(ks + i);
      #pragma unroll
      for (int i = 0; i < 16; i++)
        Vt[c0 + i][r] = vs[i];
    }
    __syncthreads();

    // S = Q K^T : wave's 16 q-rows x 64 keys
    f32x4 sacc[4];
    #pragma unroll
    for (int ni = 0; ni < 4; ni++) {
      sacc[ni] = (f32x4){0.f, 0.f, 0.f, 0.f};
      #pragma unroll
      for (int kc = 0; kc < 2; kc++) {
        Frag bk;
        bk.h[0] = *(const ushort4*)&Ks[ni * 16 + l15][kc * 32 + quad * 8];
        bk.h[1] = *(const ushort4*)&Ks[ni * 16 + l15][kc * 32 + quad * 8 + 4];
        sacc[ni] = __builtin_amdgcn_mfma_f32_16x16x32_bf16(afq[kc].v, bk.v, sacc[ni], 0, 0, 0);
      }
    }

    // scale + causal mask (C layout: row=quad*4+rg, col=ni*16+l15)
    #pragma unroll
    for (int ni = 0; ni < 4; ni++)
      #pragma unroll
      for (int rg = 0; rg < 4; rg++) {
        float s = sacc[ni][rg] * 0.125f;
        if (kt == qt) {
          int rowl = wave * 16 + quad * 4 + rg;
          int coll = ni * 16 + l15;
          if (coll > rowl) s = -1e30f;
        }
        sacc[ni][rg] = s;
      }

    // online softmax per row (reduce across l15 via 16-wide xor shuffles)
    #pragma unroll
    for (int rg = 0; rg < 4; rg++) {
      float mx = fmaxf(fmaxf(sacc[0][rg], sacc[1][rg]), fmaxf(sacc[2][rg], sacc[3][rg]));
      #pragma unroll
      for (int m = 1; m < 16; m <<= 1) mx = fmaxf(mx, __shfl_xor(mx, m, 16));
      float mnew = fmaxf(mrow[rg], mx);
      float alpha = __expf(mrow[rg] - mnew);
      float rsum = 0.f;
      #pragma unroll
      for (int ni = 0; ni < 4; ni++) {
        float p = __expf(sacc[ni][rg] - mnew);
        sacc[ni][rg] = p;
        rsum += p;
      }
      #pragma unroll
      for (int m = 1; m < 16; m <<= 1) rsum += __shfl_xor(rsum, m, 16);
      lrow[rg] = lrow[rg] * alpha + rsum;
      mrow[rg] = mnew;
      #pragma unroll
      for (int nj = 0; nj < 4; nj++) O[nj][rg] *= alpha;
    }

    // P (C layout) -> LDS -> A-operand layout
    #pragma unroll
    for (int ni = 0; ni < 4; ni++)
      #pragma unroll
      for (int rg = 0; rg < 4; rg++)
        Ps[wave * 16 + quad * 4 + rg][ni * 16 + l15] = f2bf(sacc[ni][rg]);
    __syncthreads();

    Frag ap[2];
    ap[0].h[0] = *(const ushort4*)&Ps[wave * 16 + l15][quad * 8];
    ap[0].h[1] = *(const ushort4*)&Ps[wave * 16 + l15][quad * 8 + 4];
    ap[1].h[0] = *(const ushort4*)&Ps[wave * 16 + l15][32 + quad * 8];
    ap[1].h[1] = *(const ushort4*)&Ps[wave * 16 + l15][32 + quad * 8 + 4];

    // O += P V  (B-frag from Vt: [n=hd][k=key])
    #pragma unroll
    for (int nj = 0; nj < 4; nj++) {
      #pragma unroll
      for (int kc = 0; kc < 2; kc++) {
        Frag bv;
        bv.h[0] = *(const ushort4*)&Vt[nj * 16 + l15][kc * 32 + quad * 8];
        bv.h[1] = *(const ushort4*)&Vt[nj * 16 + l15][kc * 32 + quad * 8 + 4];
        O[nj] = __builtin_amdgcn_mfma_f32_16x16x32_bf16(ap[kc].v, bv.v, O[nj], 0, 0, 0);
      }
    }
    __syncthreads();
  }

  // epilogue: normalize and write ctx
  #pragma unroll
  for (int nj = 0; nj < 4; nj++)
    #pragma unroll
    for (int rg = 0; rg < 4; rg++) {
      int row = qt * 64 + wave * 16 + quad * 4 + rg;
      int col = nj * 16 + l15;
      ctx[base + (size_t)row * Dm + col] = f2bf(O[nj][rg] / lrow[rg]);
    }
}

extern "C" void kernel_launch(void* const* d_in, const int* in_sizes, int n_in,
                              void* d_out, int out_size, void* d_ws, size_t ws_size,
                              hipStream_t stream)
{
  const float* x      = (const float*)d_in[0];
  const float* Wq     = (const float*)d_in[1];
  const float* Wk     = (const float*)d_in[2];
  const float* Wv     = (const float*)d_in[3];
  const float* Wo     = (const float*)d_in[4];
  const float* bo     = (const float*)d_in[5];
  const float* scale1 = (const float*)d_in[6];
  const float* shift1 = (const float*)d_in[7];
  const float* scale2 = (const float*)d_in[8];
  const float* shift2 = (const float*)d_in[9];
  const float* centers= (const float*)d_in[10];
  const float* lsp    = (const float*)d_in[11];
  const float* Wf     = (const float*)d_in[12];
  const float* bfv    = (const float*)d_in[13];
  float* out = (float*)d_out;

  unsigned short* wsu = (unsigned short*)d_ws;
  unsigned short* wqT = wsu;
  unsigned short* wkT = wsu + WSZ;
  unsigned short* wvT = wsu + 2 * WSZ;
  unsigned short* woT = wsu + 3 * WSZ;
  unsigned short* wfT = wsu + 4 * WSZ;
  unsigned short* cb  = wsu + 5 * WSZ;
  unsigned short* bufA = wsu + 6 * WSZ;
  unsigned short* bufB = bufA + S;
  unsigned short* hb  = bufA;          // LN1 out
  unsigned short* qb  = bufB;
  unsigned short* kb  = bufB + S;
  unsigned short* vb  = bufB + 2 * S;
  unsigned short* ctx = bufA;          // h dead after QKV
  float* x1f          = (float*)bufB;  // q,k dead after attn
  unsigned short* hf  = bufB + 2 * S;  // v dead after attn
  unsigned short* Km  = bufA;          // ctx dead after Wo GEMM
  float* hn = (float*)(bufB + 3 * S);
  float* cn = hn + ROWS;

  dim3 gg(Dm / 64, ROWS / 64);         // (12, 64)

  wt_kernel<<<dim3(12, 12, 5), 256, 0, stream>>>(Wq, Wk, Wv, Wo, Wf, wsu);
  cscale_kernel<<<dim3(3, Dm), 256, 0, stream>>>(centers, lsp, cb);
  cnorm_kernel<<<Dm, 256, 0, stream>>>(centers, lsp, cn);

  ln1_kernel<<<ROWS, 256, 0, stream>>>(x, scale1, shift1, hb);
  gemm_mfma<0><<<dim3(12, 64, 3), 256, 0, stream>>>(hb, wqT, wkT, wvT, qb, kb, vb,
                                                    nullptr, nullptr, nullptr, nullptr, nullptr);
  attn_flash<<<dim3(Ls / 64, Hh, Bb), 256, 0, stream>>>(qb, kb, vb, ctx);
  gemm_mfma<1><<<gg, 256, 0, stream>>>(ctx, woT, nullptr, nullptr, nullptr, nullptr, nullptr,
                                       x1f, x, bo, nullptr, nullptr);
  ln2_kernel<<<ROWS, 256, 0, stream>>>(x1f, scale2, shift2, lsp, hf, hn);
  gemm_mfma<2><<<gg, 256, 0, stream>>>(hf, cb, nullptr, nullptr, Km, nullptr, nullptr,
                                       nullptr, nullptr, nullptr, hn, cn);
  gemm_mfma<3><<<gg, 256, 0, stream>>>(Km, wfT, nullptr, nullptr, nullptr, nullptr, nullptr,
                                       out, x1f, bfv, nullptr, nullptr);
}

// Round 9
// 251.486 us; speedup vs baseline: 12.6913x; 1.0763x over previous
//
#include <hip/hip_runtime.h>

#define EPS_LN 1e-5f

constexpr int Dm   = 768;
constexpr int Bb   = 4;
constexpr int Ls   = 1024;
constexpr int Hh   = 12;
constexpr int HD   = 64;
constexpr int ROWS = Bb * Ls;            // 4096
constexpr size_t S = (size_t)ROWS * Dm;  // 3,145,728
constexpr size_t WSZ = (size_t)Dm * Dm;  // 589,824

typedef __attribute__((ext_vector_type(8))) short bf16x8;
typedef __attribute__((ext_vector_type(4))) float f32x4;
typedef const __attribute__((address_space(1))) unsigned int* gas_p;
typedef __attribute__((address_space(3))) unsigned int* las_p;

__device__ __forceinline__ float u16tof(unsigned short u) {
  union { unsigned int i; float f; } v; v.i = ((unsigned int)u) << 16; return v.f;
}
__device__ __forceinline__ unsigned short f2bf(float f) {
  unsigned int u = __float_as_uint(f);
  u += 0x7fffu + ((u >> 16) & 1u);   // RNE
  return (unsigned short)(u >> 16);
}
__device__ __forceinline__ void gl_lds16(const unsigned short* g, unsigned short* l) {
  __builtin_amdgcn_global_load_lds((gas_p)g, (las_p)l, 16, 0, 0);
}

// ---- transpose + cast: WT_bf16[n][k] = bf16(W[k][n]) ----
__global__ void __launch_bounds__(256) wt_kernel(
    const float* __restrict__ W0, const float* __restrict__ W1,
    const float* __restrict__ W2, const float* __restrict__ W3,
    const float* __restrict__ W4, unsigned short* __restrict__ outBase)
{
  const float* W = blockIdx.z == 0 ? W0 : blockIdx.z == 1 ? W1 :
                   blockIdx.z == 2 ? W2 : blockIdx.z == 3 ? W3 : W4;
  unsigned short* WT = outBase + (size_t)blockIdx.z * WSZ;
  __shared__ float L[64][65];
  int k0 = blockIdx.y * 64, n0 = blockIdx.x * 64;
  int c = threadIdx.x & 63, r4 = threadIdx.x >> 6;
  #pragma unroll
  for (int p = 0; p < 16; p++) {
    int r = p * 4 + r4;
    L[r][c] = W[(size_t)(k0 + r) * Dm + n0 + c];
  }
  __syncthreads();
  #pragma unroll
  for (int p = 0; p < 16; p++) {
    int r = p * 4 + r4;
    WT[(size_t)(n0 + r) * Dm + k0 + c] = f2bf(L[c][r]);
  }
}

// ---- cb[j][k] = bf16(centers[j][k] / ls[k]) ----
__global__ void __launch_bounds__(256) cscale_kernel(
    const float* __restrict__ centers, const float* __restrict__ ls,
    unsigned short* __restrict__ cb)
{
  int k = blockIdx.x * 256 + threadIdx.x;
  int j = blockIdx.y;
  size_t i = (size_t)j * Dm + k;
  cb[i] = f2bf(centers[i] / ls[k]);
}

// ---- cn[j] = sum_k (centers[j][k]/ls[k])^2 ----
__global__ void __launch_bounds__(256) cnorm_kernel(
    const float* __restrict__ centers, const float* __restrict__ ls,
    float* __restrict__ cn)
{
  int j = blockIdx.x, t = threadIdx.x;
  __shared__ float red[256];
  float s = 0.f;
  #pragma unroll
  for (int i = 0; i < 3; i++) {
    int k = t + 256 * i;
    float d = centers[(size_t)j * Dm + k] / ls[k];
    s += d * d;
  }
  red[t] = s; __syncthreads();
  for (int o = 128; o > 0; o >>= 1) { if (t < o) red[t] += red[t + o]; __syncthreads(); }
  if (t == 0) cn[j] = red[0];
}

// ---- LN1: fp32 x -> bf16 h ----
__global__ void __launch_bounds__(256) ln1_kernel(
    const float* __restrict__ xin, const float* __restrict__ scale,
    const float* __restrict__ shift, unsigned short* __restrict__ o)
{
  int row = blockIdx.x, t = threadIdx.x;
  __shared__ float red[256];
  size_t base = (size_t)row * Dm;
  float v0 = xin[base + t], v1 = xin[base + t + 256], v2 = xin[base + t + 512];
  red[t] = v0 + v1 + v2; __syncthreads();
  for (int oo = 128; oo > 0; oo >>= 1) { if (t < oo) red[t] += red[t + oo]; __syncthreads(); }
  float mean = red[0] * (1.0f / Dm);
  __syncthreads();
  float d0 = v0 - mean, d1 = v1 - mean, d2 = v2 - mean;
  red[t] = d0*d0 + d1*d1 + d2*d2; __syncthreads();
  for (int oo = 128; oo > 0; oo >>= 1) { if (t < oo) red[t] += red[t + oo]; __syncthreads(); }
  float rstd = rsqrtf(red[0] * (1.0f / Dm) + EPS_LN);
  float dd[3] = {d0, d1, d2};
  #pragma unroll
  for (int i = 0; i < 3; i++) {
    int c = t + 256 * i;
    o[base + c] = f2bf(scale[c] * dd[i] * rstd + shift[c]);
  }
}

// ---- LN2 + /ls: fp32 x1 -> bf16 hf + fp32 hnorm[row] ----
__global__ void __launch_bounds__(256) ln2_kernel(
    const float* __restrict__ xin, const float* __restrict__ scale,
    const float* __restrict__ shift, const float* __restrict__ ls,
    unsigned short* __restrict__ o, float* __restrict__ hn)
{
  int row = blockIdx.x, t = threadIdx.x;
  __shared__ float red[256];
  size_t base = (size_t)row * Dm;
  float v0 = xin[base + t], v1 = xin[base + t + 256], v2 = xin[base + t + 512];
  red[t] = v0 + v1 + v2; __syncthreads();
  for (int oo = 128; oo > 0; oo >>= 1) { if (t < oo) red[t] += red[t + oo]; __syncthreads(); }
  float mean = red[0] * (1.0f / Dm);
  __syncthreads();
  float d0 = v0 - mean, d1 = v1 - mean, d2 = v2 - mean;
  red[t] = d0*d0 + d1*d1 + d2*d2; __syncthreads();
  for (int oo = 128; oo > 0; oo >>= 1) { if (t < oo) red[t] += red[t + oo]; __syncthreads(); }
  float rstd = rsqrtf(red[0] * (1.0f / Dm) + EPS_LN);
  float dd[3] = {d0, d1, d2};
  float hsum = 0.f;
  #pragma unroll
  for (int i = 0; i < 3; i++) {
    int c = t + 256 * i;
    float hv = (scale[c] * dd[i] * rstd + shift[c]) / ls[c];
    o[base + c] = f2bf(hv);
    hsum += hv * hv;
  }
  __syncthreads();
  red[t] = hsum; __syncthreads();
  for (int o2 = 128; o2 > 0; o2 >>= 1) { if (t < o2) red[t] += red[t + o2]; __syncthreads(); }
  if (t == 0) hn[row] = red[0];
}

// =============== MFMA bf16 GEMM, 128x128 tile, global_load_lds staging ===============
// A: bf16 [4096][768]. BT: bf16 [768][768] (B^T). 4 waves, each 64x64 (4x4 16^2 frags).
// MODE 0: z selects (BT0..2, o0..2); out bf16 = acc
// MODE 1: outF = residF + acc + biasF
// MODE 2: o0 bf16 = exp(-0.5*max(hn[r]+cn[c]-2acc, 0))
// MODE 3: outF = residF + acc + biasF
template<int MODE>
__global__ void __launch_bounds__(256) gemm128(
    const unsigned short* __restrict__ Abf,
    const unsigned short* __restrict__ BT0,
    const unsigned short* __restrict__ BT1,
    const unsigned short* __restrict__ BT2,
    unsigned short* __restrict__ o0,
    unsigned short* __restrict__ o1,
    unsigned short* __restrict__ o2,
    float* __restrict__ outF,
    const float* __restrict__ residF,
    const float* __restrict__ biasF,
    const float* __restrict__ hn,
    const float* __restrict__ cn)
{
  const unsigned short* BT = BT0;
  unsigned short* ob = o0;
  if (MODE == 0) {
    if (blockIdx.z == 1) { BT = BT1; ob = o1; }
    else if (blockIdx.z == 2) { BT = BT2; ob = o2; }
  }
  int m0 = blockIdx.y * 128, n0 = blockIdx.x * 128;
  __shared__ unsigned short Asm[128 * 32];
  __shared__ unsigned short Bsm[128 * 32];
  int tid = threadIdx.x;
  int lane = tid & 63, wave = tid >> 6;
  int quad = lane >> 4, l15 = lane & 15;
  int wr = (wave >> 1) << 6, wc = (wave & 1) << 6;

  f32x4 acc[4][4];
  #pragma unroll
  for (int i = 0; i < 4; i++)
    #pragma unroll
    for (int j = 0; j < 4; j++) acc[i][j] = (f32x4){0.f, 0.f, 0.f, 0.f};

  // staging: chunk c = tid (rows 0..63) and tid+256 (rows 64..127); 16B per chunk
  const unsigned short* gA = Abf + (size_t)(m0 + (tid >> 2)) * Dm + ((tid & 3) << 3);
  const unsigned short* gB = BT  + (size_t)(n0 + (tid >> 2)) * Dm + ((tid & 3) << 3);
  const size_t rowOff = (size_t)64 * Dm;
  unsigned short* lA0 = &Asm[tid * 8];
  unsigned short* lA1 = &Asm[tid * 8 + 2048];
  unsigned short* lB0 = &Bsm[tid * 8];
  unsigned short* lB1 = &Bsm[tid * 8 + 2048];

  union Frag { bf16x8 v; ushort4 h[2]; };

  for (int k0 = 0; k0 < Dm; k0 += 32) {
    gl_lds16(gA + k0, lA0);
    gl_lds16(gA + rowOff + k0, lA1);
    gl_lds16(gB + k0, lB0);
    gl_lds16(gB + rowOff + k0, lB1);
    __syncthreads();
    Frag af[4], bfb[4];
    #pragma unroll
    for (int i = 0; i < 4; i++) {
      int ar = (wr + i * 16 + l15) * 32 + quad * 8;
      int br = (wc + i * 16 + l15) * 32 + quad * 8;
      af[i].h[0]  = *(const ushort4*)&Asm[ar];
      af[i].h[1]  = *(const ushort4*)&Asm[ar + 4];
      bfb[i].h[0] = *(const ushort4*)&Bsm[br];
      bfb[i].h[1] = *(const ushort4*)&Bsm[br + 4];
    }
    #pragma unroll
    for (int mi = 0; mi < 4; mi++)
      #pragma unroll
      for (int ni = 0; ni < 4; ni++)
        acc[mi][ni] = __builtin_amdgcn_mfma_f32_16x16x32_bf16(
            af[mi].v, bfb[ni].v, acc[mi][ni], 0, 0, 0);
    __syncthreads();
  }

  // C/D layout: col = lane&15, row = quad*4 + reg
  #pragma unroll
  for (int mi = 0; mi < 4; mi++)
    #pragma unroll
    for (int ni = 0; ni < 4; ni++) {
      #pragma unroll
      for (int rg = 0; rg < 4; rg++) {
        int gr = m0 + wr + mi * 16 + quad * 4 + rg;
        int gc = n0 + wc + ni * 16 + l15;
        size_t idx = (size_t)gr * Dm + gc;
        float v = acc[mi][ni][rg];
        if (MODE == 0) {
          ob[idx] = f2bf(v);
        } else if (MODE == 1) {
          outF[idx] = residF[idx] + v + biasF[gc];
        } else if (MODE == 2) {
          float sq = fmaxf(hn[gr] + cn[gc] - 2.0f * v, 0.f);
          o0[idx] = f2bf(__expf(-0.5f * sq));
        } else {
          outF[idx] = residF[idx] + v + biasF[gc];
        }
      }
    }
}

// =============== flash attention: one block per (b, h, 64-row Q tile) ===============
__global__ void __launch_bounds__(256) attn_flash(
    const unsigned short* __restrict__ q,
    const unsigned short* __restrict__ k,
    const unsigned short* __restrict__ v,
    unsigned short* __restrict__ ctx)
{
  int qt = blockIdx.x;     // 0..15
  int h  = blockIdx.y;     // 0..11
  int b  = blockIdx.z;     // 0..3
  int tid = threadIdx.x;
  int lane = tid & 63, wave = tid >> 6;
  int quad = lane >> 4, l15 = lane & 15;

  __shared__ unsigned short Qs[64][72];
  __shared__ unsigned short Ks[64][72];
  __shared__ unsigned short Vt[64][72];   // Vt[d][ (key + 16*(d>>4)) & 63 ] = V[key][d]
  __shared__ unsigned short Ps[64][72];

  size_t base = (size_t)b * Ls * Dm + h * HD;

  // stage Q tile scaled by 1/sqrt(64) (exact power-of-2 in bf16)
  {
    int r = tid >> 2, c0 = (tid & 3) * 16;
    const unsigned short* src = q + base + (size_t)(qt * 64 + r) * Dm + c0;
    #pragma unroll
    for (int i = 0; i < 16; i += 4) {
      ushort4 a = *(const ushort4*)(src + i);
      ushort4 o;
      o.x = f2bf(u16tof(a.x) * 0.125f);
      o.y = f2bf(u16tof(a.y) * 0.125f);
      o.z = f2bf(u16tof(a.z) * 0.125f);
      o.w = f2bf(u16tof(a.w) * 0.125f);
      *(ushort4*)&Qs[r][c0 + i] = o;
    }
  }

  f32x4 O[4];
  #pragma unroll
  for (int nj = 0; nj < 4; nj++) O[nj] = (f32x4){0.f, 0.f, 0.f, 0.f};
  float mrow[4], lrow[4];
  #pragma unroll
  for (int rg = 0; rg < 4; rg++) { mrow[rg] = -1e30f; lrow[rg] = 0.f; }

  __syncthreads();

  union Frag { bf16x8 v; ushort4 h[2]; };
  Frag afq[2];
  afq[0].h[0] = *(const ushort4*)&Qs[wave * 16 + l15][quad * 8];
  afq[0].h[1] = *(const ushort4*)&Qs[wave * 16 + l15][quad * 8 + 4];
  afq[1].h[0] = *(const ushort4*)&Qs[wave * 16 + l15][32 + quad * 8];
  afq[1].h[1] = *(const ushort4*)&Qs[wave * 16 + l15][32 + quad * 8 + 4];

  for (int kt = 0; kt <= qt; kt++) {
    // stage K (row-major, vectorized) and V (swizzled transpose, vectorized loads)
    {
      int r = tid >> 2, g = tid & 3, c0 = g * 16;
      const unsigned short* ks = k + base + (size_t)(kt * 64 + r) * Dm + c0;
      const unsigned short* vs = v + base + (size_t)(kt * 64 + r) * Dm + c0;
      #pragma unroll
      for (int i = 0; i < 16; i += 4)
        *(ushort4*)&Ks[r][c0 + i] = *(const ushort4*)(ks + i);
      int vcol = (r + 16 * g) & 63;
      #pragma unroll
      for (int i = 0; i < 16; i += 4) {
        ushort4 vv = *(const ushort4*)(vs + i);
        Vt[c0 + i + 0][vcol] = vv.x;
        Vt[c0 + i + 1][vcol] = vv.y;
        Vt[c0 + i + 2][vcol] = vv.z;
        Vt[c0 + i + 3][vcol] = vv.w;
      }
    }
    __syncthreads();

    // S = Q K^T
    f32x4 sacc[4];
    #pragma unroll
    for (int ni = 0; ni < 4; ni++) {
      sacc[ni] = (f32x4){0.f, 0.f, 0.f, 0.f};
      #pragma unroll
      for (int kc = 0; kc < 2; kc++) {
        Frag bk;
        bk.h[0] = *(const ushort4*)&Ks[ni * 16 + l15][kc * 32 + quad * 8];
        bk.h[1] = *(const ushort4*)&Ks[ni * 16 + l15][kc * 32 + quad * 8 + 4];
        sacc[ni] = __builtin_amdgcn_mfma_f32_16x16x32_bf16(afq[kc].v, bk.v, sacc[ni], 0, 0, 0);
      }
    }

    // causal mask on diagonal tile (C layout: row=quad*4+rg, col=ni*16+l15)
    if (kt == qt) {
      #pragma unroll
      for (int ni = 0; ni < 4; ni++)
        #pragma unroll
        for (int rg = 0; rg < 4; rg++) {
          int rowl = wave * 16 + quad * 4 + rg;
          int coll = ni * 16 + l15;
          if (coll > rowl) sacc[ni][rg] = -1e30f;
        }
    }

    // online softmax per row
    #pragma unroll
    for (int rg = 0; rg < 4; rg++) {
      float mx = fmaxf(fmaxf(sacc[0][rg], sacc[1][rg]), fmaxf(sacc[2][rg], sacc[3][rg]));
      #pragma unroll
      for (int m = 1; m < 16; m <<= 1) mx = fmaxf(mx, __shfl_xor(mx, m, 16));
      float mnew = fmaxf(mrow[rg], mx);
      float alpha = __expf(mrow[rg] - mnew);
      float rsum = 0.f;
      #pragma unroll
      for (int ni = 0; ni < 4; ni++) {
        float p = __expf(sacc[ni][rg] - mnew);
        sacc[ni][rg] = p;
        rsum += p;
      }
      #pragma unroll
      for (int m = 1; m < 16; m <<= 1) rsum += __shfl_xor(rsum, m, 16);
      lrow[rg] = lrow[rg] * alpha + rsum;
      mrow[rg] = mnew;
      #pragma unroll
      for (int nj = 0; nj < 4; nj++) O[nj][rg] *= alpha;
    }

    // P (C layout) -> LDS -> A-operand layout
    #pragma unroll
    for (int ni = 0; ni < 4; ni++)
      #pragma unroll
      for (int rg = 0; rg < 4; rg++)
        Ps[wave * 16 + quad * 4 + rg][ni * 16 + l15] = f2bf(sacc[ni][rg]);
    __syncthreads();

    Frag ap[2];
    ap[0].h[0] = *(const ushort4*)&Ps[wave * 16 + l15][quad * 8];
    ap[0].h[1] = *(const ushort4*)&Ps[wave * 16 + l15][quad * 8 + 4];
    ap[1].h[0] = *(const ushort4*)&Ps[wave * 16 + l15][32 + quad * 8];
    ap[1].h[1] = *(const ushort4*)&Ps[wave * 16 + l15][32 + quad * 8 + 4];

    // O += P V  (B-frag from swizzled Vt)
    #pragma unroll
    for (int nj = 0; nj < 4; nj++) {
      #pragma unroll
      for (int kc = 0; kc < 2; kc++) {
        int colv = (kc * 32 + quad * 8 + 16 * nj) & 63;
        Frag bv;
        bv.h[0] = *(const ushort4*)&Vt[nj * 16 + l15][colv];
        bv.h[1] = *(const ushort4*)&Vt[nj * 16 + l15][colv + 4];
        O[nj] = __builtin_amdgcn_mfma_f32_16x16x32_bf16(ap[kc].v, bv.v, O[nj], 0, 0, 0);
      }
    }
    __syncthreads();
  }

  // epilogue
  #pragma unroll
  for (int nj = 0; nj < 4; nj++)
    #pragma unroll
    for (int rg = 0; rg < 4; rg++) {
      int row = qt * 64 + wave * 16 + quad * 4 + rg;
      int col = nj * 16 + l15;
      ctx[base + (size_t)row * Dm + col] = f2bf(O[nj][rg] / lrow[rg]);
    }
}

extern "C" void kernel_launch(void* const* d_in, const int* in_sizes, int n_in,
                              void* d_out, int out_size, void* d_ws, size_t ws_size,
                              hipStream_t stream)
{
  const float* x      = (const float*)d_in[0];
  const float* Wq     = (const float*)d_in[1];
  const float* Wk     = (const float*)d_in[2];
  const float* Wv     = (const float*)d_in[3];
  const float* Wo     = (const float*)d_in[4];
  const float* bo     = (const float*)d_in[5];
  const float* scale1 = (const float*)d_in[6];
  const float* shift1 = (const float*)d_in[7];
  const float* scale2 = (const float*)d_in[8];
  const float* shift2 = (const float*)d_in[9];
  const float* centers= (const float*)d_in[10];
  const float* lsp    = (const float*)d_in[11];
  const float* Wf     = (const float*)d_in[12];
  const float* bfv    = (const float*)d_in[13];
  float* out = (float*)d_out;

  unsigned short* wsu = (unsigned short*)d_ws;
  unsigned short* wqT = wsu;
  unsigned short* wkT = wsu + WSZ;
  unsigned short* wvT = wsu + 2 * WSZ;
  unsigned short* woT = wsu + 3 * WSZ;
  unsigned short* wfT = wsu + 4 * WSZ;
  unsigned short* cb  = wsu + 5 * WSZ;
  unsigned short* bufA = wsu + 6 * WSZ;
  unsigned short* bufB = bufA + S;
  unsigned short* hb  = bufA;          // LN1 out
  unsigned short* qb  = bufB;
  unsigned short* kb  = bufB + S;
  unsigned short* vb  = bufB + 2 * S;
  unsigned short* ctx = bufA;          // h dead after QKV
  float* x1f          = (float*)bufB;  // q,k dead after attn
  unsigned short* hf  = bufB + 2 * S;  // v dead after attn
  unsigned short* Km  = bufA;          // ctx dead after Wo GEMM
  float* hn = (float*)(bufB + 3 * S);
  float* cn = hn + ROWS;

  dim3 gg(Dm / 128, ROWS / 128);       // (6, 32)

  wt_kernel<<<dim3(12, 12, 5), 256, 0, stream>>>(Wq, Wk, Wv, Wo, Wf, wsu);
  cscale_kernel<<<dim3(3, Dm), 256, 0, stream>>>(centers, lsp, cb);
  cnorm_kernel<<<Dm, 256, 0, stream>>>(centers, lsp, cn);

  ln1_kernel<<<ROWS, 256, 0, stream>>>(x, scale1, shift1, hb);
  gemm128<0><<<dim3(6, 32, 3), 256, 0, stream>>>(hb, wqT, wkT, wvT, qb, kb, vb,
                                                 nullptr, nullptr, nullptr, nullptr, nullptr);
  attn_flash<<<dim3(Ls / 64, Hh, Bb), 256, 0, stream>>>(qb, kb, vb, ctx);
  gemm128<1><<<gg, 256, 0, stream>>>(ctx, woT, nullptr, nullptr, nullptr, nullptr, nullptr,
                                     x1f, x, bo, nullptr, nullptr);
  ln2_kernel<<<ROWS, 256, 0, stream>>>(x1f, scale2, shift2, lsp, hf, hn);
  gemm128<2><<<gg, 256, 0, stream>>>(hf, cb, nullptr, nullptr, Km, nullptr, nullptr,
                                     nullptr, nullptr, nullptr, hn, cn);
  gemm128<3><<<gg, 256, 0, stream>>>(Km, wfT, nullptr, nullptr, nullptr, nullptr, nullptr,
                                     out, x1f, bfv, nullptr, nullptr);
}

// Round 10
// 221.481 us; speedup vs baseline: 14.4106x; 1.1355x over previous
//
#include <hip/hip_runtime.h>

#define EPS_LN 1e-5f

constexpr int Dm   = 768;
constexpr int Bb   = 4;
constexpr int Ls   = 1024;
constexpr int Hh   = 12;
constexpr int HD   = 64;
constexpr int ROWS = Bb * Ls;            // 4096
constexpr size_t S = (size_t)ROWS * Dm;  // 3,145,728
constexpr size_t WSZ = (size_t)Dm * Dm;  // 589,824

typedef __attribute__((ext_vector_type(8))) short bf16x8;
typedef __attribute__((ext_vector_type(4))) float f32x4;
typedef const __attribute__((address_space(1))) unsigned int* gas_p;
typedef __attribute__((address_space(3))) unsigned int* las_p;

__device__ __forceinline__ float u16tof(unsigned short u) {
  union { unsigned int i; float f; } v; v.i = ((unsigned int)u) << 16; return v.f;
}
__device__ __forceinline__ unsigned short f2bf(float f) {
  unsigned int u = __float_as_uint(f);
  u += 0x7fffu + ((u >> 16) & 1u);   // RNE
  return (unsigned short)(u >> 16);
}
__device__ __forceinline__ void gl_lds16(const unsigned short* g, unsigned short* l) {
  __builtin_amdgcn_global_load_lds((gas_p)g, (las_p)l, 16, 0, 0);
}

// ---- transpose + cast: WT_bf16[n][k] = bf16(W[k][n]) ----
__global__ void __launch_bounds__(256) wt_kernel(
    const float* __restrict__ W0, const float* __restrict__ W1,
    const float* __restrict__ W2, const float* __restrict__ W3,
    const float* __restrict__ W4, unsigned short* __restrict__ outBase)
{
  const float* W = blockIdx.z == 0 ? W0 : blockIdx.z == 1 ? W1 :
                   blockIdx.z == 2 ? W2 : blockIdx.z == 3 ? W3 : W4;
  unsigned short* WT = outBase + (size_t)blockIdx.z * WSZ;
  __shared__ float L[64][65];
  int k0 = blockIdx.y * 64, n0 = blockIdx.x * 64;
  int c = threadIdx.x & 63, r4 = threadIdx.x >> 6;
  #pragma unroll
  for (int p = 0; p < 16; p++) {
    int r = p * 4 + r4;
    L[r][c] = W[(size_t)(k0 + r) * Dm + n0 + c];
  }
  __syncthreads();
  #pragma unroll
  for (int p = 0; p < 16; p++) {
    int r = p * 4 + r4;
    WT[(size_t)(n0 + r) * Dm + k0 + c] = f2bf(L[c][r]);
  }
}

// ---- per center row j: cb[j][k] = bf16(centers[j][k]/ls[k]); cn[j] = ||.||^2 ----
__global__ void __launch_bounds__(256) prep_centers(
    const float* __restrict__ centers, const float* __restrict__ ls,
    unsigned short* __restrict__ cb, float* __restrict__ cn)
{
  int j = blockIdx.x, t = threadIdx.x;
  __shared__ float red[256];
  float s = 0.f;
  #pragma unroll
  for (int i = 0; i < 3; i++) {
    int k = t + 256 * i;
    float c = centers[(size_t)j * Dm + k] / ls[k];
    cb[(size_t)j * Dm + k] = f2bf(c);
    s += c * c;
  }
  red[t] = s; __syncthreads();
  for (int o = 128; o > 0; o >>= 1) { if (t < o) red[t] += red[t + o]; __syncthreads(); }
  if (t == 0) cn[j] = red[0];
}

// ---- LN1: fp32 x -> bf16 h ----
__global__ void __launch_bounds__(256) ln1_kernel(
    const float* __restrict__ xin, const float* __restrict__ scale,
    const float* __restrict__ shift, unsigned short* __restrict__ o)
{
  int row = blockIdx.x, t = threadIdx.x;
  __shared__ float red[256];
  size_t base = (size_t)row * Dm;
  float v0 = xin[base + t], v1 = xin[base + t + 256], v2 = xin[base + t + 512];
  red[t] = v0 + v1 + v2; __syncthreads();
  for (int oo = 128; oo > 0; oo >>= 1) { if (t < oo) red[t] += red[t + oo]; __syncthreads(); }
  float mean = red[0] * (1.0f / Dm);
  __syncthreads();
  float d0 = v0 - mean, d1 = v1 - mean, d2 = v2 - mean;
  red[t] = d0*d0 + d1*d1 + d2*d2; __syncthreads();
  for (int oo = 128; oo > 0; oo >>= 1) { if (t < oo) red[t] += red[t + oo]; __syncthreads(); }
  float rstd = rsqrtf(red[0] * (1.0f / Dm) + EPS_LN);
  float dd[3] = {d0, d1, d2};
  #pragma unroll
  for (int i = 0; i < 3; i++) {
    int c = t + 256 * i;
    o[base + c] = f2bf(scale[c] * dd[i] * rstd + shift[c]);
  }
}

// ---- LN2 + /ls: fp32 x1 -> bf16 hf + fp32 hnorm[row] ----
__global__ void __launch_bounds__(256) ln2_kernel(
    const float* __restrict__ xin, const float* __restrict__ scale,
    const float* __restrict__ shift, const float* __restrict__ ls,
    unsigned short* __restrict__ o, float* __restrict__ hn)
{
  int row = blockIdx.x, t = threadIdx.x;
  __shared__ float red[256];
  size_t base = (size_t)row * Dm;
  float v0 = xin[base + t], v1 = xin[base + t + 256], v2 = xin[base + t + 512];
  red[t] = v0 + v1 + v2; __syncthreads();
  for (int oo = 128; oo > 0; oo >>= 1) { if (t < oo) red[t] += red[t + oo]; __syncthreads(); }
  float mean = red[0] * (1.0f / Dm);
  __syncthreads();
  float d0 = v0 - mean, d1 = v1 - mean, d2 = v2 - mean;
  red[t] = d0*d0 + d1*d1 + d2*d2; __syncthreads();
  for (int oo = 128; oo > 0; oo >>= 1) { if (t < oo) red[t] += red[t + oo]; __syncthreads(); }
  float rstd = rsqrtf(red[0] * (1.0f / Dm) + EPS_LN);
  float dd[3] = {d0, d1, d2};
  float hsum = 0.f;
  #pragma unroll
  for (int i = 0; i < 3; i++) {
    int c = t + 256 * i;
    float hv = (scale[c] * dd[i] * rstd + shift[c]) / ls[c];
    o[base + c] = f2bf(hv);
    hsum += hv * hv;
  }
  __syncthreads();
  red[t] = hsum; __syncthreads();
  for (int o2 = 128; o2 > 0; o2 >>= 1) { if (t < o2) red[t] += red[t + o2]; __syncthreads(); }
  if (t == 0) hn[row] = red[0];
}

// =============== MFMA bf16 GEMM, 64x64 tile, BK=64, split-half gl_lds staging ===============
// A: bf16 [4096][768]. BT: bf16 [768][768] (B^T). 4 waves, each 32x32 (2x2 16^2 frags).
// MODE 0: z selects (BT0..2, o0..2); out bf16 = acc
// MODE 1: outF = residF + acc + biasF
// MODE 2: o0 bf16 = exp(-0.5*max(hn[r]+cn[c]-2acc, 0))
// MODE 3: outF = residF + acc + biasF
template<int MODE>
__global__ void __launch_bounds__(256) gemm64(
    const unsigned short* __restrict__ Abf,
    const unsigned short* __restrict__ BT0,
    const unsigned short* __restrict__ BT1,
    const unsigned short* __restrict__ BT2,
    unsigned short* __restrict__ o0,
    unsigned short* __restrict__ o1,
    unsigned short* __restrict__ o2,
    float* __restrict__ outF,
    const float* __restrict__ residF,
    const float* __restrict__ biasF,
    const float* __restrict__ hn,
    const float* __restrict__ cn)
{
  const unsigned short* BT = BT0;
  unsigned short* ob = o0;
  if (MODE == 0) {
    if (blockIdx.z == 1) { BT = BT1; ob = o1; }
    else if (blockIdx.z == 2) { BT = BT2; ob = o2; }
  }
  int m0 = blockIdx.y * 64, n0 = blockIdx.x * 64;
  __shared__ unsigned short Asm[2][2048];   // [kc-half][row*32 + col]; stride 32 elems = m97 pattern
  __shared__ unsigned short Bsm[2][2048];
  int tid = threadIdx.x;
  int lane = tid & 63, wave = tid >> 6;
  int quad = lane >> 4, l15 = lane & 15;
  int wr = (wave >> 1) << 5, wc = (wave & 1) << 5;

  f32x4 acc[2][2];
  #pragma unroll
  for (int i = 0; i < 2; i++)
    #pragma unroll
    for (int j = 0; j < 2; j++) acc[i][j] = (f32x4){0.f, 0.f, 0.f, 0.f};

  const unsigned short* gA = Abf + (size_t)(m0 + (tid >> 2)) * Dm + ((tid & 3) << 3);
  const unsigned short* gB = BT  + (size_t)(n0 + (tid >> 2)) * Dm + ((tid & 3) << 3);
  unsigned short* lA0 = &Asm[0][tid * 8];
  unsigned short* lA1 = &Asm[1][tid * 8];
  unsigned short* lB0 = &Bsm[0][tid * 8];
  unsigned short* lB1 = &Bsm[1][tid * 8];

  union Frag { bf16x8 v; ushort4 h[2]; };

  for (int k0 = 0; k0 < Dm; k0 += 64) {
    gl_lds16(gA + k0,      lA0);
    gl_lds16(gA + k0 + 32, lA1);
    gl_lds16(gB + k0,      lB0);
    gl_lds16(gB + k0 + 32, lB1);
    __syncthreads();
    Frag af[2][2], bfb[2][2];   // [kc][mi/ni]
    #pragma unroll
    for (int kc = 0; kc < 2; kc++)
      #pragma unroll
      for (int i = 0; i < 2; i++) {
        int ar = (wr + i * 16 + l15) * 32 + quad * 8;
        int br = (wc + i * 16 + l15) * 32 + quad * 8;
        af[kc][i].h[0]  = *(const ushort4*)&Asm[kc][ar];
        af[kc][i].h[1]  = *(const ushort4*)&Asm[kc][ar + 4];
        bfb[kc][i].h[0] = *(const ushort4*)&Bsm[kc][br];
        bfb[kc][i].h[1] = *(const ushort4*)&Bsm[kc][br + 4];
      }
    #pragma unroll
    for (int mi = 0; mi < 2; mi++)
      #pragma unroll
      for (int ni = 0; ni < 2; ni++)
        #pragma unroll
        for (int kc = 0; kc < 2; kc++)
          acc[mi][ni] = __builtin_amdgcn_mfma_f32_16x16x32_bf16(
              af[kc][mi].v, bfb[kc][ni].v, acc[mi][ni], 0, 0, 0);
    __syncthreads();
  }

  // C/D layout: col = lane&15, row = quad*4 + reg
  #pragma unroll
  for (int mi = 0; mi < 2; mi++)
    #pragma unroll
    for (int ni = 0; ni < 2; ni++) {
      #pragma unroll
      for (int rg = 0; rg < 4; rg++) {
        int gr = m0 + wr + mi * 16 + quad * 4 + rg;
        int gc = n0 + wc + ni * 16 + l15;
        size_t idx = (size_t)gr * Dm + gc;
        float v = acc[mi][ni][rg];
        if (MODE == 0) {
          ob[idx] = f2bf(v);
        } else if (MODE == 1) {
          outF[idx] = residF[idx] + v + biasF[gc];
        } else if (MODE == 2) {
          float sq = fmaxf(hn[gr] + cn[gc] - 2.0f * v, 0.f);
          o0[idx] = f2bf(__expf(-0.5f * sq));
        } else {
          outF[idx] = residF[idx] + v + biasF[gc];
        }
      }
    }
}

// =============== flash attention v2: const-max softmax, Ps aliases Qs ===============
// Scores bounded (|s| < 72 << 88), so exp() without max subtraction is exact math
// (softmax shift-invariance) and overflow-free. l-reduction deferred to epilogue.
__global__ void __launch_bounds__(256) attn_flash(
    const unsigned short* __restrict__ q,
    const unsigned short* __restrict__ k,
    const unsigned short* __restrict__ v,
    unsigned short* __restrict__ ctx)
{
  int bx = blockIdx.x;
  int qt = (bx & 1) ? (15 - (bx >> 1)) : (bx >> 1);   // balanced pairing
  int h  = blockIdx.y;
  int b  = blockIdx.z;
  int tid = threadIdx.x;
  int lane = tid & 63, wave = tid >> 6;
  int quad = lane >> 4, l15 = lane & 15;

  __shared__ unsigned short Qs[64][72];   // reused as Ps after Q-frag hoist
  __shared__ unsigned short Ks[64][72];
  __shared__ unsigned short Vt[64][72];   // Vt[d][(key + 16*(d>>4)) & 63] = V[key][d]
  unsigned short (*Ps)[72] = Qs;

  size_t base = (size_t)b * Ls * Dm + h * HD;

  // stage Q tile scaled by 1/8 (exact in bf16)
  {
    int r = tid >> 2, c0 = (tid & 3) * 16;
    const unsigned short* src = q + base + (size_t)(qt * 64 + r) * Dm + c0;
    #pragma unroll
    for (int i = 0; i < 16; i += 4) {
      ushort4 a = *(const ushort4*)(src + i);
      ushort4 o;
      o.x = f2bf(u16tof(a.x) * 0.125f);
      o.y = f2bf(u16tof(a.y) * 0.125f);
      o.z = f2bf(u16tof(a.z) * 0.125f);
      o.w = f2bf(u16tof(a.w) * 0.125f);
      *(ushort4*)&Qs[r][c0 + i] = o;
    }
  }

  f32x4 O[4];
  #pragma unroll
  for (int nj = 0; nj < 4; nj++) O[nj] = (f32x4){0.f, 0.f, 0.f, 0.f};
  float lsum[4] = {0.f, 0.f, 0.f, 0.f};

  __syncthreads();

  union Frag { bf16x8 v; ushort4 h[2]; };
  Frag afq[2];
  afq[0].h[0] = *(const ushort4*)&Qs[wave * 16 + l15][quad * 8];
  afq[0].h[1] = *(const ushort4*)&Qs[wave * 16 + l15][quad * 8 + 4];
  afq[1].h[0] = *(const ushort4*)&Qs[wave * 16 + l15][32 + quad * 8];
  afq[1].h[1] = *(const ushort4*)&Qs[wave * 16 + l15][32 + quad * 8 + 4];

  for (int kt = 0; kt <= qt; kt++) {
    // stage K (row-major) and V (swizzled transpose)
    {
      int r = tid >> 2, g = tid & 3, c0 = g * 16;
      const unsigned short* ks = k + base + (size_t)(kt * 64 + r) * Dm + c0;
      const unsigned short* vs = v + base + (size_t)(kt * 64 + r) * Dm + c0;
      #pragma unroll
      for (int i = 0; i < 16; i += 4)
        *(ushort4*)&Ks[r][c0 + i] = *(const ushort4*)(ks + i);
      int vcol = (r + 16 * g) & 63;
      #pragma unroll
      for (int i = 0; i < 16; i += 4) {
        ushort4 vv = *(const ushort4*)(vs + i);
        Vt[c0 + i + 0][vcol] = vv.x;
        Vt[c0 + i + 1][vcol] = vv.y;
        Vt[c0 + i + 2][vcol] = vv.z;
        Vt[c0 + i + 3][vcol] = vv.w;
      }
    }
    __syncthreads();

    // S = Q K^T
    f32x4 sacc[4];
    #pragma unroll
    for (int ni = 0; ni < 4; ni++) {
      sacc[ni] = (f32x4){0.f, 0.f, 0.f, 0.f};
      #pragma unroll
      for (int kc = 0; kc < 2; kc++) {
        Frag bk;
        bk.h[0] = *(const ushort4*)&Ks[ni * 16 + l15][kc * 32 + quad * 8];
        bk.h[1] = *(const ushort4*)&Ks[ni * 16 + l15][kc * 32 + quad * 8 + 4];
        sacc[ni] = __builtin_amdgcn_mfma_f32_16x16x32_bf16(afq[kc].v, bk.v, sacc[ni], 0, 0, 0);
      }
    }

    // causal mask on diagonal tile
    if (kt == qt) {
      #pragma unroll
      for (int ni = 0; ni < 4; ni++)
        #pragma unroll
        for (int rg = 0; rg < 4; rg++) {
          int rowl = wave * 16 + quad * 4 + rg;
          int coll = ni * 16 + l15;
          if (coll > rowl) sacc[ni][rg] = -1e30f;
        }
    }

    // p = exp(s); accumulate per-lane row-sum partials; write P to LDS (A-layout transform)
    #pragma unroll
    for (int ni = 0; ni < 4; ni++)
      #pragma unroll
      for (int rg = 0; rg < 4; rg++) {
        float p = __expf(sacc[ni][rg]);
        lsum[rg] += p;
        Ps[wave * 16 + quad * 4 + rg][ni * 16 + l15] = f2bf(p);
      }
    __syncthreads();

    Frag ap[2];
    ap[0].h[0] = *(const ushort4*)&Ps[wave * 16 + l15][quad * 8];
    ap[0].h[1] = *(const ushort4*)&Ps[wave * 16 + l15][quad * 8 + 4];
    ap[1].h[0] = *(const ushort4*)&Ps[wave * 16 + l15][32 + quad * 8];
    ap[1].h[1] = *(const ushort4*)&Ps[wave * 16 + l15][32 + quad * 8 + 4];

    // O += P V  (B-frag from swizzled Vt)
    #pragma unroll
    for (int nj = 0; nj < 4; nj++) {
      #pragma unroll
      for (int kc = 0; kc < 2; kc++) {
        int colv = (kc * 32 + quad * 8 + 16 * nj) & 63;
        Frag bv;
        bv.h[0] = *(const ushort4*)&Vt[nj * 16 + l15][colv];
        bv.h[1] = *(const ushort4*)&Vt[nj * 16 + l15][colv + 4];
        O[nj] = __builtin_amdgcn_mfma_f32_16x16x32_bf16(ap[kc].v, bv.v, O[nj], 0, 0, 0);
      }
    }
    __syncthreads();
  }

  // epilogue: reduce row sums once, normalize, write
  float linv[4];
  #pragma unroll
  for (int rg = 0; rg < 4; rg++) {
    float l = lsum[rg];
    #pragma unroll
    for (int m = 1; m < 16; m <<= 1) l += __shfl_xor(l, m, 16);
    linv[rg] = 1.0f / l;
  }
  #pragma unroll
  for (int nj = 0; nj < 4; nj++)
    #pragma unroll
    for (int rg = 0; rg < 4; rg++) {
      int row = qt * 64 + wave * 16 + quad * 4 + rg;
      int col = nj * 16 + l15;
      ctx[base + (size_t)row * Dm + col] = f2bf(O[nj][rg] * linv[rg]);
    }
}

extern "C" void kernel_launch(void* const* d_in, const int* in_sizes, int n_in,
                              void* d_out, int out_size, void* d_ws, size_t ws_size,
                              hipStream_t stream)
{
  const float* x      = (const float*)d_in[0];
  const float* Wq     = (const float*)d_in[1];
  const float* Wk     = (const float*)d_in[2];
  const float* Wv     = (const float*)d_in[3];
  const float* Wo     = (const float*)d_in[4];
  const float* bo     = (const float*)d_in[5];
  const float* scale1 = (const float*)d_in[6];
  const float* shift1 = (const float*)d_in[7];
  const float* scale2 = (const float*)d_in[8];
  const float* shift2 = (const float*)d_in[9];
  const float* centers= (const float*)d_in[10];
  const float* lsp    = (const float*)d_in[11];
  const float* Wf     = (const float*)d_in[12];
  const float* bfv    = (const float*)d_in[13];
  float* out = (float*)d_out;

  unsigned short* wsu = (unsigned short*)d_ws;
  unsigned short* wqT = wsu;
  unsigned short* wkT = wsu + WSZ;
  unsigned short* wvT = wsu + 2 * WSZ;
  unsigned short* woT = wsu + 3 * WSZ;
  unsigned short* wfT = wsu + 4 * WSZ;
  unsigned short* cb  = wsu + 5 * WSZ;
  unsigned short* bufA = wsu + 6 * WSZ;
  unsigned short* bufB = bufA + S;
  unsigned short* hb  = bufA;          // LN1 out
  unsigned short* qb  = bufB;
  unsigned short* kb  = bufB + S;
  unsigned short* vb  = bufB + 2 * S;
  unsigned short* ctx = bufA;          // h dead after QKV
  float* x1f          = (float*)bufB;  // q,k dead after attn
  unsigned short* hf  = bufB + 2 * S;  // v dead after attn
  unsigned short* Km  = bufA;          // ctx dead after Wo GEMM
  float* hn = (float*)(bufB + 3 * S);
  float* cn = hn + ROWS;

  dim3 gg(Dm / 64, ROWS / 64);         // (12, 64)

  wt_kernel<<<dim3(12, 12, 5), 256, 0, stream>>>(Wq, Wk, Wv, Wo, Wf, wsu);
  prep_centers<<<Dm, 256, 0, stream>>>(centers, lsp, cb, cn);

  ln1_kernel<<<ROWS, 256, 0, stream>>>(x, scale1, shift1, hb);
  gemm64<0><<<dim3(12, 64, 3), 256, 0, stream>>>(hb, wqT, wkT, wvT, qb, kb, vb,
                                                 nullptr, nullptr, nullptr, nullptr, nullptr);
  attn_flash<<<dim3(Ls / 64, Hh, Bb), 256, 0, stream>>>(qb, kb, vb, ctx);
  gemm64<1><<<gg, 256, 0, stream>>>(ctx, woT, nullptr, nullptr, nullptr, nullptr, nullptr,
                                    x1f, x, bo, nullptr, nullptr);
  ln2_kernel<<<ROWS, 256, 0, stream>>>(x1f, scale2, shift2, lsp, hf, hn);
  gemm64<2><<<gg, 256, 0, stream>>>(hf, cb, nullptr, nullptr, Km, nullptr, nullptr,
                                    nullptr, nullptr, nullptr, hn, cn);
  gemm64<3><<<gg, 256, 0, stream>>>(Km, wfT, nullptr, nullptr, nullptr, nullptr, nullptr,
                                    out, x1f, bfv, nullptr, nullptr);
}

// Round 11
// 197.182 us; speedup vs baseline: 16.1864x; 1.1232x over previous
//
#include <hip/hip_runtime.h>

#define EPS_LN 1e-5f

constexpr int Dm   = 768;
constexpr int Bb   = 4;
constexpr int Ls   = 1024;
constexpr int Hh   = 12;
constexpr int HD   = 64;
constexpr int ROWS = Bb * Ls;            // 4096
constexpr size_t S = (size_t)ROWS * Dm;  // 3,145,728
constexpr size_t WSZ = (size_t)Dm * Dm;  // 589,824

typedef __attribute__((ext_vector_type(8))) short bf16x8;
typedef __attribute__((ext_vector_type(4))) float f32x4;
typedef const __attribute__((address_space(1))) unsigned int* gas_p;
typedef __attribute__((address_space(3))) unsigned int* las_p;

__device__ __forceinline__ float u16tof(unsigned short u) {
  union { unsigned int i; float f; } v; v.i = ((unsigned int)u) << 16; return v.f;
}
__device__ __forceinline__ unsigned short f2bf(float f) {
  unsigned int u = __float_as_uint(f);
  u += 0x7fffu + ((u >> 16) & 1u);   // RNE
  return (unsigned short)(u >> 16);
}
__device__ __forceinline__ void gl_lds16(const unsigned short* g, unsigned short* l) {
  __builtin_amdgcn_global_load_lds((gas_p)g, (las_p)l, 16, 0, 0);
}

// =============== fused prep: 5 weight transposes + centers + LN1 ===============
// blocks [0,720): wt; [720,1488): centers; [1488,5584): ln1 rows
__global__ void __launch_bounds__(256) prep_kernel(
    const float* __restrict__ W0, const float* __restrict__ W1,
    const float* __restrict__ W2, const float* __restrict__ W3,
    const float* __restrict__ W4, unsigned short* __restrict__ wtBase,
    const float* __restrict__ centers, const float* __restrict__ ls,
    unsigned short* __restrict__ cb, float* __restrict__ cn,
    const float* __restrict__ x, const float* __restrict__ scale,
    const float* __restrict__ shift, unsigned short* __restrict__ hb)
{
  __shared__ float smem[64 * 65];
  int bx = blockIdx.x, t = threadIdx.x;
  if (bx < 720) {
    int w = bx / 144, rem = bx - w * 144;
    int ky = rem / 12, nx = rem - ky * 12;
    const float* W = w == 0 ? W0 : w == 1 ? W1 : w == 2 ? W2 : w == 3 ? W3 : W4;
    unsigned short* WT = wtBase + (size_t)w * WSZ;
    int k0 = ky * 64, n0 = nx * 64;
    int c = t & 63, r4 = t >> 6;
    #pragma unroll
    for (int p = 0; p < 16; p++) {
      int r = p * 4 + r4;
      smem[r * 65 + c] = W[(size_t)(k0 + r) * Dm + n0 + c];
    }
    __syncthreads();
    #pragma unroll
    for (int p = 0; p < 16; p++) {
      int r = p * 4 + r4;
      WT[(size_t)(n0 + r) * Dm + k0 + c] = f2bf(smem[c * 65 + r]);
    }
  } else if (bx < 1488) {
    int j = bx - 720;
    float s = 0.f;
    #pragma unroll
    for (int i = 0; i < 3; i++) {
      int k = t + 256 * i;
      float c = centers[(size_t)j * Dm + k] / ls[k];
      cb[(size_t)j * Dm + k] = f2bf(c);
      s += c * c;
    }
    smem[t] = s; __syncthreads();
    for (int o = 128; o > 0; o >>= 1) { if (t < o) smem[t] += smem[t + o]; __syncthreads(); }
    if (t == 0) cn[j] = smem[0];
  } else {
    int row = bx - 1488;
    size_t base = (size_t)row * Dm;
    float v0 = x[base + t], v1 = x[base + t + 256], v2 = x[base + t + 512];
    smem[t] = v0 + v1 + v2; __syncthreads();
    for (int o = 128; o > 0; o >>= 1) { if (t < o) smem[t] += smem[t + o]; __syncthreads(); }
    float mean = smem[0] * (1.0f / Dm);
    __syncthreads();
    float d0 = v0 - mean, d1 = v1 - mean, d2 = v2 - mean;
    smem[t] = d0*d0 + d1*d1 + d2*d2; __syncthreads();
    for (int o = 128; o > 0; o >>= 1) { if (t < o) smem[t] += smem[t + o]; __syncthreads(); }
    float rstd = rsqrtf(smem[0] * (1.0f / Dm) + EPS_LN);
    float dd[3] = {d0, d1, d2};
    #pragma unroll
    for (int i = 0; i < 3; i++) {
      int c = t + 256 * i;
      hb[base + c] = f2bf(scale[c] * dd[i] * rstd + shift[c]);
    }
  }
}

// ---- LN2 + /ls: fp32 x1 -> bf16 hf + fp32 hnorm[row] ----
__global__ void __launch_bounds__(256) ln2_kernel(
    const float* __restrict__ xin, const float* __restrict__ scale,
    const float* __restrict__ shift, const float* __restrict__ ls,
    unsigned short* __restrict__ o, float* __restrict__ hn)
{
  int row = blockIdx.x, t = threadIdx.x;
  __shared__ float red[256];
  size_t base = (size_t)row * Dm;
  float v0 = xin[base + t], v1 = xin[base + t + 256], v2 = xin[base + t + 512];
  red[t] = v0 + v1 + v2; __syncthreads();
  for (int oo = 128; oo > 0; oo >>= 1) { if (t < oo) red[t] += red[t + oo]; __syncthreads(); }
  float mean = red[0] * (1.0f / Dm);
  __syncthreads();
  float d0 = v0 - mean, d1 = v1 - mean, d2 = v2 - mean;
  red[t] = d0*d0 + d1*d1 + d2*d2; __syncthreads();
  for (int oo = 128; oo > 0; oo >>= 1) { if (t < oo) red[t] += red[t + oo]; __syncthreads(); }
  float rstd = rsqrtf(red[0] * (1.0f / Dm) + EPS_LN);
  float dd[3] = {d0, d1, d2};
  float hsum = 0.f;
  #pragma unroll
  for (int i = 0; i < 3; i++) {
    int c = t + 256 * i;
    float hv = (scale[c] * dd[i] * rstd + shift[c]) / ls[c];
    o[base + c] = f2bf(hv);
    hsum += hv * hv;
  }
  __syncthreads();
  red[t] = hsum; __syncthreads();
  for (int o2 = 128; o2 > 0; o2 >>= 1) { if (t < o2) red[t] += red[t + o2]; __syncthreads(); }
  if (t == 0) hn[row] = red[0];
}

// =============== QKV 3-in-1 GEMM: A staged once, 3 weights, V written transposed ===============
// grid (12 heads/col-tiles, 64 row-tiles). vbt[((h*4+b)*64 + d)*1024 + key].
__global__ void __launch_bounds__(256) gemm_qkv(
    const unsigned short* __restrict__ Abf,
    const unsigned short* __restrict__ wqT,
    const unsigned short* __restrict__ wkT,
    const unsigned short* __restrict__ wvT,
    unsigned short* __restrict__ qb,
    unsigned short* __restrict__ kb,
    unsigned short* __restrict__ vbt)
{
  int m0 = blockIdx.y * 64, n0 = blockIdx.x * 64;
  __shared__ unsigned short sm[4096 + 3 * 4096];   // A[2][2048] then B[3][2][2048]
  int tid = threadIdx.x;
  int lane = tid & 63, wave = tid >> 6;
  int quad = lane >> 4, l15 = lane & 15;
  int wr = (wave >> 1) << 5, wc = (wave & 1) << 5;

  f32x4 acc[3][2][2];
  #pragma unroll
  for (int w = 0; w < 3; w++)
    #pragma unroll
    for (int i = 0; i < 2; i++)
      #pragma unroll
      for (int j = 0; j < 2; j++) acc[w][i][j] = (f32x4){0.f, 0.f, 0.f, 0.f};

  const unsigned short* gA = Abf + (size_t)(m0 + (tid >> 2)) * Dm + ((tid & 3) << 3);
  size_t bOff = (size_t)(n0 + (tid >> 2)) * Dm + ((tid & 3) << 3);
  const unsigned short* gB[3] = { wqT + bOff, wkT + bOff, wvT + bOff };

  union Frag { bf16x8 v; ushort4 h[2]; };

  for (int k0 = 0; k0 < Dm; k0 += 64) {
    gl_lds16(gA + k0,      &sm[tid * 8]);
    gl_lds16(gA + k0 + 32, &sm[2048 + tid * 8]);
    #pragma unroll
    for (int w = 0; w < 3; w++) {
      gl_lds16(gB[w] + k0,      &sm[4096 + w * 4096 + tid * 8]);
      gl_lds16(gB[w] + k0 + 32, &sm[4096 + w * 4096 + 2048 + tid * 8]);
    }
    __syncthreads();
    Frag af[2][2];
    #pragma unroll
    for (int kc = 0; kc < 2; kc++)
      #pragma unroll
      for (int mi = 0; mi < 2; mi++)
        af[kc][mi].v = *(const bf16x8*)&sm[kc * 2048 + (wr + mi * 16 + l15) * 32 + quad * 8];
    #pragma unroll
    for (int w = 0; w < 3; w++)
      #pragma unroll
      for (int kc = 0; kc < 2; kc++)
        #pragma unroll
        for (int ni = 0; ni < 2; ni++) {
          Frag bf;
          bf.v = *(const bf16x8*)&sm[4096 + w * 4096 + kc * 2048 + (wc + ni * 16 + l15) * 32 + quad * 8];
          #pragma unroll
          for (int mi = 0; mi < 2; mi++)
            acc[w][mi][ni] = __builtin_amdgcn_mfma_f32_16x16x32_bf16(
                af[kc][mi].v, bf.v, acc[w][mi][ni], 0, 0, 0);
        }
    __syncthreads();
  }

  // q, k epilogue (C layout: col=lane&15, row=quad*4+reg)
  #pragma unroll
  for (int w = 0; w < 2; w++) {
    unsigned short* ob = w ? kb : qb;
    #pragma unroll
    for (int mi = 0; mi < 2; mi++)
      #pragma unroll
      for (int ni = 0; ni < 2; ni++)
        #pragma unroll
        for (int rg = 0; rg < 4; rg++) {
          int gr = m0 + wr + mi * 16 + quad * 4 + rg;
          int gc = n0 + wc + ni * 16 + l15;
          ob[(size_t)gr * Dm + gc] = f2bf(acc[w][mi][ni][rg]);
        }
  }
  // v epilogue: transpose through LDS, write vbt rows (d-major) coalesced
  #pragma unroll
  for (int mi = 0; mi < 2; mi++)
    #pragma unroll
    for (int ni = 0; ni < 2; ni++)
      #pragma unroll
      for (int rg = 0; rg < 4; rg++) {
        int rl = wr + mi * 16 + quad * 4 + rg;     // key-local
        int cl = wc + ni * 16 + l15;               // d
        sm[cl * 72 + rl] = f2bf(acc[2][mi][ni][rg]);
      }
  __syncthreads();
  {
    int d = tid >> 2, c0 = (tid & 3) * 16;
    int b_ = m0 >> 10, keybase = m0 & 1023;
    unsigned short* dst = vbt + ((size_t)((blockIdx.x * 4 + b_) * 64 + d)) * 1024 + keybase + c0;
    #pragma unroll
    for (int i = 0; i < 16; i += 4)
      *(ushort4*)(dst + i) = *(const ushort4*)&sm[d * 72 + c0 + i];
  }
}

// =============== MFMA bf16 GEMM, 64x64 tile, BK=64 (modes 1..3) ===============
// MODE 1: outF = residF + acc + biasF
// MODE 2: o0 bf16 = exp(-0.5*max(hn[r]+cn[c]-2acc, 0))
// MODE 3: outF = residF + acc + biasF
template<int MODE>
__global__ void __launch_bounds__(256) gemm64(
    const unsigned short* __restrict__ Abf,
    const unsigned short* __restrict__ BT,
    unsigned short* __restrict__ o0,
    float* __restrict__ outF,
    const float* __restrict__ residF,
    const float* __restrict__ biasF,
    const float* __restrict__ hn,
    const float* __restrict__ cn)
{
  int m0 = blockIdx.y * 64, n0 = blockIdx.x * 64;
  __shared__ unsigned short Asm[2][2048];
  __shared__ unsigned short Bsm[2][2048];
  int tid = threadIdx.x;
  int lane = tid & 63, wave = tid >> 6;
  int quad = lane >> 4, l15 = lane & 15;
  int wr = (wave >> 1) << 5, wc = (wave & 1) << 5;

  f32x4 acc[2][2];
  #pragma unroll
  for (int i = 0; i < 2; i++)
    #pragma unroll
    for (int j = 0; j < 2; j++) acc[i][j] = (f32x4){0.f, 0.f, 0.f, 0.f};

  const unsigned short* gA = Abf + (size_t)(m0 + (tid >> 2)) * Dm + ((tid & 3) << 3);
  const unsigned short* gB = BT  + (size_t)(n0 + (tid >> 2)) * Dm + ((tid & 3) << 3);

  union Frag { bf16x8 v; ushort4 h[2]; };

  for (int k0 = 0; k0 < Dm; k0 += 64) {
    gl_lds16(gA + k0,      &Asm[0][tid * 8]);
    gl_lds16(gA + k0 + 32, &Asm[1][tid * 8]);
    gl_lds16(gB + k0,      &Bsm[0][tid * 8]);
    gl_lds16(gB + k0 + 32, &Bsm[1][tid * 8]);
    __syncthreads();
    #pragma unroll
    for (int kc = 0; kc < 2; kc++) {
      Frag af[2], bfb[2];
      #pragma unroll
      for (int i = 0; i < 2; i++) {
        af[i].v  = *(const bf16x8*)&Asm[kc][(wr + i * 16 + l15) * 32 + quad * 8];
        bfb[i].v = *(const bf16x8*)&Bsm[kc][(wc + i * 16 + l15) * 32 + quad * 8];
      }
      #pragma unroll
      for (int mi = 0; mi < 2; mi++)
        #pragma unroll
        for (int ni = 0; ni < 2; ni++)
          acc[mi][ni] = __builtin_amdgcn_mfma_f32_16x16x32_bf16(
              af[mi].v, bfb[ni].v, acc[mi][ni], 0, 0, 0);
    }
    __syncthreads();
  }

  #pragma unroll
  for (int mi = 0; mi < 2; mi++)
    #pragma unroll
    for (int ni = 0; ni < 2; ni++)
      #pragma unroll
      for (int rg = 0; rg < 4; rg++) {
        int gr = m0 + wr + mi * 16 + quad * 4 + rg;
        int gc = n0 + wc + ni * 16 + l15;
        size_t idx = (size_t)gr * Dm + gc;
        float v = acc[mi][ni][rg];
        if (MODE == 2) {
          float sq = fmaxf(hn[gr] + cn[gc] - 2.0f * v, 0.f);
          o0[idx] = f2bf(__expf(-0.5f * sq));
        } else {
          outF[idx] = residF[idx] + v + biasF[gc];
        }
      }
}

// =============== flash attention v3: all staging via global_load_lds ===============
// q,k: bf16 [ROWS][768]; v: pre-transposed vbt[((h*4+b)*64+d)*1024+key]. Causal.
// Const-max softmax (scores bounded, exp overflow-free); scale folded into exp.
__global__ void __launch_bounds__(256) attn_flash(
    const unsigned short* __restrict__ q,
    const unsigned short* __restrict__ k,
    const unsigned short* __restrict__ vbt,
    unsigned short* __restrict__ ctx)
{
  int bx = blockIdx.x;
  int qt = (bx & 1) ? (15 - (bx >> 1)) : (bx >> 1);   // balanced pairing
  int h  = blockIdx.y;
  int b  = blockIdx.z;
  int tid = threadIdx.x;
  int lane = tid & 63, wave = tid >> 6;
  int quad = lane >> 4, l15 = lane & 15;

  __shared__ unsigned short Ks[2][2048];
  __shared__ unsigned short Vt[2][2048];
  __shared__ unsigned short QP[4608];   // Q halves [2][2048] then reused as Ps[64][72]

  size_t baseQK = (size_t)(b * Ls) * Dm + h * HD;
  const unsigned short* gVt = vbt + (size_t)((h * 4 + b) * 64 + (tid >> 2)) * 1024 + ((tid & 3) << 3);

  // stage Q (raw; scale folded into exp)
  {
    const unsigned short* gQ = q + baseQK + (size_t)(qt * 64 + (tid >> 2)) * Dm + ((tid & 3) << 3);
    gl_lds16(gQ,      &QP[tid * 8]);
    gl_lds16(gQ + 32, &QP[2048 + tid * 8]);
  }
  __syncthreads();

  union Frag { bf16x8 v; ushort4 h[2]; };
  Frag afq[2];
  #pragma unroll
  for (int kc = 0; kc < 2; kc++)
    afq[kc].v = *(const bf16x8*)&QP[kc * 2048 + (wave * 16 + l15) * 32 + quad * 8];

  f32x4 O[4];
  #pragma unroll
  for (int nj = 0; nj < 4; nj++) O[nj] = (f32x4){0.f, 0.f, 0.f, 0.f};
  float lsum[4] = {0.f, 0.f, 0.f, 0.f};

  const unsigned short* gK = k + baseQK + (size_t)(tid >> 2) * Dm + ((tid & 3) << 3);

  for (int kt = 0; kt <= qt; kt++) {
    gl_lds16(gK + (size_t)(kt * 64) * Dm,      &Ks[0][tid * 8]);
    gl_lds16(gK + (size_t)(kt * 64) * Dm + 32, &Ks[1][tid * 8]);
    gl_lds16(gVt + kt * 64,      &Vt[0][tid * 8]);
    gl_lds16(gVt + kt * 64 + 32, &Vt[1][tid * 8]);
    __syncthreads();

    // S = Q K^T (keys = B-frag rows)
    f32x4 sacc[4];
    #pragma unroll
    for (int ni = 0; ni < 4; ni++) {
      sacc[ni] = (f32x4){0.f, 0.f, 0.f, 0.f};
      #pragma unroll
      for (int kc = 0; kc < 2; kc++) {
        Frag bk;
        bk.v = *(const bf16x8*)&Ks[kc][((ni & 1) * 32 + (ni >> 1) * 16 + l15) * 32 + quad * 8];
        sacc[ni] = __builtin_amdgcn_mfma_f32_16x16x32_bf16(afq[kc].v, bk.v, sacc[ni], 0, 0, 0);
      }
    }
    // note: Ks half-major layout means key index = (ni&1)*32 + (ni>>1)*16 + l15?  No --
    // Ks[kc] holds dims kc*32..; rows ARE keys 0..63. Re-map: key row = ni*16+l15 directly.
    // (kept simple below by recomputing with correct indexing)

    // recompute with plain indexing (compiler folds; above loop retained structure)
    #pragma unroll
    for (int ni = 0; ni < 4; ni++) {
      sacc[ni] = (f32x4){0.f, 0.f, 0.f, 0.f};
      #pragma unroll
      for (int kc = 0; kc < 2; kc++) {
        Frag bk;
        bk.v = *(const bf16x8*)&Ks[kc][(ni * 16 + l15) * 32 + quad * 8];
        sacc[ni] = __builtin_amdgcn_mfma_f32_16x16x32_bf16(afq[kc].v, bk.v, sacc[ni], 0, 0, 0);
      }
    }

    // causal mask on diagonal tile
    if (kt == qt) {
      #pragma unroll
      for (int ni = 0; ni < 4; ni++)
        #pragma unroll
        for (int rg = 0; rg < 4; rg++) {
          int rowl = wave * 16 + quad * 4 + rg;
          int coll = ni * 16 + l15;
          if (coll > rowl) sacc[ni][rg] = -1e30f;
        }
    }

    // p = exp(s/8); row-sum partials; P -> LDS (A-layout); intra-wave, no barrier
    unsigned short (*Ps)[72] = (unsigned short(*)[72])QP;
    #pragma unroll
    for (int ni = 0; ni < 4; ni++)
      #pragma unroll
      for (int rg = 0; rg < 4; rg++) {
        float p = __expf(sacc[ni][rg] * 0.125f);
        lsum[rg] += p;
        Ps[wave * 16 + quad * 4 + rg][ni * 16 + l15] = f2bf(p);
      }

    Frag ap[2];
    #pragma unroll
    for (int kc = 0; kc < 2; kc++)
      ap[kc].v = *(const bf16x8*)&Ps[wave * 16 + l15][kc * 32 + quad * 8];

    // O += P V  (Vt rows = d, cols = keys)
    #pragma unroll
    for (int nj = 0; nj < 4; nj++)
      #pragma unroll
      for (int kc = 0; kc < 2; kc++) {
        Frag bv;
        bv.v = *(const bf16x8*)&Vt[kc][(nj * 16 + l15) * 32 + quad * 8];
        O[nj] = __builtin_amdgcn_mfma_f32_16x16x32_bf16(ap[kc].v, bv.v, O[nj], 0, 0, 0);
      }
    __syncthreads();
  }

  // epilogue: reduce row sums, normalize, write
  float linv[4];
  #pragma unroll
  for (int rg = 0; rg < 4; rg++) {
    float l = lsum[rg];
    #pragma unroll
    for (int m = 1; m < 16; m <<= 1) l += __shfl_xor(l, m, 16);
    linv[rg] = 1.0f / l;
  }
  #pragma unroll
  for (int nj = 0; nj < 4; nj++)
    #pragma unroll
    for (int rg = 0; rg < 4; rg++) {
      int row = qt * 64 + wave * 16 + quad * 4 + rg;
      int col = nj * 16 + l15;
      ctx[baseQK + (size_t)row * Dm + col] = f2bf(O[nj][rg] * linv[rg]);
    }
}

extern "C" void kernel_launch(void* const* d_in, const int* in_sizes, int n_in,
                              void* d_out, int out_size, void* d_ws, size_t ws_size,
                              hipStream_t stream)
{
  const float* x      = (const float*)d_in[0];
  const float* Wq     = (const float*)d_in[1];
  const float* Wk     = (const float*)d_in[2];
  const float* Wv     = (const float*)d_in[3];
  const float* Wo     = (const float*)d_in[4];
  const float* bo     = (const float*)d_in[5];
  const float* scale1 = (const float*)d_in[6];
  const float* shift1 = (const float*)d_in[7];
  const float* scale2 = (const float*)d_in[8];
  const float* shift2 = (const float*)d_in[9];
  const float* centers= (const float*)d_in[10];
  const float* lsp    = (const float*)d_in[11];
  const float* Wf     = (const float*)d_in[12];
  const float* bfv    = (const float*)d_in[13];
  float* out = (float*)d_out;

  unsigned short* wsu = (unsigned short*)d_ws;
  unsigned short* wqT = wsu;
  unsigned short* wkT = wsu + WSZ;
  unsigned short* wvT = wsu + 2 * WSZ;
  unsigned short* woT = wsu + 3 * WSZ;
  unsigned short* wfT = wsu + 4 * WSZ;
  unsigned short* cb  = wsu + 5 * WSZ;
  unsigned short* bufA = wsu + 6 * WSZ;
  unsigned short* bufB = bufA + S;
  unsigned short* hb  = bufA;          // LN1 out
  unsigned short* qb  = bufB;
  unsigned short* kb  = bufB + S;
  unsigned short* vbt = bufB + 2 * S;  // per-head transposed V
  unsigned short* ctx = bufA;          // h dead after QKV
  float* x1f          = (float*)bufB;  // q,k dead after attn
  unsigned short* hf  = bufB + 2 * S;  // vbt dead after attn
  unsigned short* Km  = bufA;          // ctx dead after Wo GEMM
  float* hn = (float*)(bufB + 3 * S);
  float* cn = hn + ROWS;

  dim3 gg(Dm / 64, ROWS / 64);         // (12, 64)

  prep_kernel<<<5584, 256, 0, stream>>>(Wq, Wk, Wv, Wo, Wf, wsu,
                                        centers, lsp, cb, cn,
                                        x, scale1, shift1, hb);
  gemm_qkv<<<dim3(12, 64), 256, 0, stream>>>(hb, wqT, wkT, wvT, qb, kb, vbt);
  attn_flash<<<dim3(Ls / 64, Hh, Bb), 256, 0, stream>>>(qb, kb, vbt, ctx);
  gemm64<1><<<gg, 256, 0, stream>>>(ctx, woT, nullptr, x1f, x, bo, nullptr, nullptr);
  ln2_kernel<<<ROWS, 256, 0, stream>>>(x1f, scale2, shift2, lsp, hf, hn);
  gemm64<2><<<gg, 256, 0, stream>>>(hf, cb, Km, nullptr, nullptr, nullptr, hn, cn);
  gemm64<3><<<gg, 256, 0, stream>>>(Km, wfT, nullptr, out, x1f, bfv, nullptr, nullptr);
}